// Round 1
// baseline (1156.790 us; speedup 1.0000x reference)
//
#include <hip/hip_runtime.h>
#include <math.h>

#define NQ 20000
#define MS 20000
#define HN 32
#define CH 128
#define DH 64
#define KTOT 20
#define KMINI 7
#define EPSN 1e-5f

// workspace layout (in floats)
#define OFF_ROWSUM 0
#define OFF_Y1     20480
#define OFF_Y2     (OFF_Y1 + NQ*DH)
#define OFF_SEG    (OFF_Y2 + NQ*DH)          // 4 * 128 floats used
#define OFF_OUTPRE (OFF_SEG + 1024)
#define OFF_BNSUM  (OFF_OUTPRE + NQ*CH)
#define OFF_BNSQ   (OFF_BNSUM + 128)

// ---------------- kernel 0: per-row sum of x (density sign test) --------------
__global__ __launch_bounds__(256) void k_rowsum(const float* __restrict__ x,
                                                float* __restrict__ rowsum) {
    int row = blockIdx.x * 4 + (threadIdx.x >> 6);
    int lane = threadIdx.x & 63;
    if (row >= MS) return;
    double s = (double)x[row * CH + lane] + (double)x[row * CH + 64 + lane];
    #pragma unroll
    for (int off = 32; off > 0; off >>= 1) s += __shfl_down(s, off, 64);
    if (lane == 0) rowsum[row] = (float)s;
}

// ---------------- kernel 1: fused dual KPConv (mini + mid), 4 rows/block ------
__global__ __launch_bounds__(256) void k_kpconv(
    const float* __restrict__ q_pts, const float* __restrict__ s_pts,
    const int* __restrict__ inds, const float* __restrict__ x,
    const float* __restrict__ kp_mini, const float* __restrict__ kp_mid,
    const float* __restrict__ w_mini, const float* __restrict__ w_mid,
    const float* __restrict__ rowsum,
    float* __restrict__ y1, float* __restrict__ y2)
{
    __shared__ __align__(16) float kpts[KTOT][3];
    __shared__ __align__(16) float nb[128][3];
    __shared__ int   nidx[128];
    __shared__ int   vcnt[4];
    __shared__ float winv[4];
    __shared__ __align__(16) float wts[4][HN][KTOT];   // per (row,h,k) influence * 1/n_num
    __shared__ __align__(16) float wt[KTOT][CH][4];    // weighted[k][c][row]
    __shared__ __align__(16) float part[128][4];

    const int t = threadIdx.x;
    const int n0 = blockIdx.x * 4;

    if (t < KTOT * 3) {
        int k = t / 3, j = t % 3;
        kpts[k][j] = (k < KMINI) ? kp_mini[k * 3 + j] : kp_mid[(k - KMINI) * 3 + j];
    }
    if (t < 4) vcnt[t] = 0;
    __syncthreads();

    // neighbor vectors + validity count
    if (t < 128) {
        int r = t >> 5, h = t & 31;
        int n = n0 + r;
        int idx = inds[n * HN + h];
        nidx[t] = idx;
        float qx = q_pts[n * 3 + 0], qy = q_pts[n * 3 + 1], qz = q_pts[n * 3 + 2];
        nb[t][0] = s_pts[idx * 3 + 0] - qx;
        nb[t][1] = s_pts[idx * 3 + 1] - qy;
        nb[t][2] = s_pts[idx * 3 + 2] - qz;
        if (rowsum[idx] > 0.0f) atomicAdd(&vcnt[r], 1);
    }
    __syncthreads();
    if (t < 4) winv[t] = 1.0f / (float)max(vcnt[t], 1);
    __syncthreads();

    // KP influences: 4*32*20 = 2560 values
    for (int tt = t; tt < 4 * HN * KTOT; tt += 256) {
        int r = tt / (HN * KTOT);
        int rem = tt % (HN * KTOT);
        int h = rem / KTOT, k = rem % KTOT;
        float dx = nb[r * HN + h][0] - kpts[k][0];
        float dy = nb[r * HN + h][1] - kpts[k][1];
        float dz = nb[r * HN + h][2] - kpts[k][2];
        float sq = dx * dx + dy * dy + dz * dz;
        float dist = sqrtf(fmaxf(sq, 1e-12f));
        float w = fmaxf(1.0f - dist * (1.0f / 0.6f), 0.0f);
        wts[r][h][k] = w * winv[r];
    }
    __syncthreads();

    // accumulate weighted[k][c] over h; group g owns rows {g, g+2}
    {
        const int g = t >> 7;
        const int c = t & 127;
        for (int rr = 0; rr < 2; ++rr) {
            const int r = g + rr * 2;
            float acc[KTOT];
            #pragma unroll
            for (int k = 0; k < KTOT; ++k) acc[k] = 0.0f;
            for (int h = 0; h < HN; ++h) {
                int idx = nidx[r * HN + h];
                float xv = x[(size_t)idx * CH + c];
                const float4* wp = (const float4*)&wts[r][h][0];
                float4 wa = wp[0], wb = wp[1], wc = wp[2], wd = wp[3], we = wp[4];
                acc[0]  += wa.x * xv; acc[1]  += wa.y * xv; acc[2]  += wa.z * xv; acc[3]  += wa.w * xv;
                acc[4]  += wb.x * xv; acc[5]  += wb.y * xv; acc[6]  += wb.z * xv; acc[7]  += wb.w * xv;
                acc[8]  += wc.x * xv; acc[9]  += wc.y * xv; acc[10] += wc.z * xv; acc[11] += wc.w * xv;
                acc[12] += wd.x * xv; acc[13] += wd.y * xv; acc[14] += wd.z * xv; acc[15] += wd.w * xv;
                acc[16] += we.x * xv; acc[17] += we.y * xv; acc[18] += we.z * xv; acc[19] += we.w * xv;
            }
            #pragma unroll
            for (int k = 0; k < KTOT; ++k) wt[k][c][r] = acc[k];
        }
    }
    __syncthreads();

    // output GEMM: out[r][d] = sum_{k,c} wt[k][c][r] * W[k][c][d]
    {
        const int d = t & 127;
        const int half = t >> 7;
        const int c0 = half * 64;
        float o0 = 0.f, o1 = 0.f, o2 = 0.f, o3 = 0.f;
        if (d < DH) {
            for (int k = 0; k < KMINI; ++k) {
                const float* wp = &w_mini[((size_t)k * CH + c0) * DH + d];
                for (int c = c0; c < c0 + 64; ++c) {
                    float wv = *wp; wp += DH;
                    const float4 wtv = *(const float4*)&wt[k][c][0];
                    o0 += wv * wtv.x; o1 += wv * wtv.y; o2 += wv * wtv.z; o3 += wv * wtv.w;
                }
            }
        } else {
            const int dd = d - DH;
            for (int k = KMINI; k < KTOT; ++k) {
                const float* wp = &w_mid[((size_t)(k - KMINI) * CH + c0) * DH + dd];
                for (int c = c0; c < c0 + 64; ++c) {
                    float wv = *wp; wp += DH;
                    const float4 wtv = *(const float4*)&wt[k][c][0];
                    o0 += wv * wtv.x; o1 += wv * wtv.y; o2 += wv * wtv.z; o3 += wv * wtv.w;
                }
            }
        }
        if (half == 1) { part[d][0] = o0; part[d][1] = o1; part[d][2] = o2; part[d][3] = o3; }
        __syncthreads();
        if (half == 0) {
            o0 += part[d][0]; o1 += part[d][1]; o2 += part[d][2]; o3 += part[d][3];
            if (d < DH) {
                y1[(size_t)(n0 + 0) * DH + d] = o0;
                y1[(size_t)(n0 + 1) * DH + d] = o1;
                y1[(size_t)(n0 + 2) * DH + d] = o2;
                y1[(size_t)(n0 + 3) * DH + d] = o3;
            } else {
                const int dd = d - DH;
                y2[(size_t)(n0 + 0) * DH + dd] = o0;
                y2[(size_t)(n0 + 1) * DH + dd] = o1;
                y2[(size_t)(n0 + 2) * DH + dd] = o2;
                y2[(size_t)(n0 + 3) * DH + dd] = o3;
            }
        }
    }
}

// ---------------- kernel 2: per-segment mean/rstd for y1 & y2 ----------------
__global__ __launch_bounds__(256) void k_segstats(
    const float* __restrict__ y1, const float* __restrict__ y2,
    const int* __restrict__ stacklen, float* __restrict__ segstats)
{
    int b = blockIdx.x >> 1, s = blockIdx.x & 1;
    const float* y = b ? y2 : y1;
    int len0 = stacklen[0];
    int start = s ? len0 : 0;
    int end = s ? NQ : len0;
    int ch = threadIdx.x & 63, grp = threadIdx.x >> 6;
    float sum = 0.f, sq = 0.f;
    for (int r = start + grp; r < end; r += 4) {
        float v = y[(size_t)r * DH + ch];
        sum += v; sq += v * v;
    }
    __shared__ float ssum[4][64], ssq[4][64];
    ssum[grp][ch] = sum; ssq[grp][ch] = sq;
    __syncthreads();
    if (threadIdx.x < 64) {
        float S = ssum[0][ch] + ssum[1][ch] + ssum[2][ch] + ssum[3][ch];
        float Q = ssq[0][ch] + ssq[1][ch] + ssq[2][ch] + ssq[3][ch];
        float cnt = (float)max(end - start, 1);
        float mean = S / cnt;
        float var = Q / cnt - mean * mean;
        float rstd = rsqrtf(fmaxf(var, 0.f) + EPSN);
        segstats[(b * 2 + s) * 128 + ch] = mean;
        segstats[(b * 2 + s) * 128 + 64 + ch] = rstd;
    }
}

// ------- kernel 3: segment-norm + midmini linear + concat + final linear ------
__global__ __launch_bounds__(256) void k_tail(
    const float* __restrict__ y1, const float* __restrict__ y2,
    const float* __restrict__ segstats, const int* __restrict__ stacklen,
    const float* __restrict__ w_midmini, const float* __restrict__ w_final,
    float* __restrict__ outpre)
{
    __shared__ __align__(16) float sbuf[8][64];    // x1n + x2n
    __shared__ __align__(16) float xc[8][128];     // [x1n | x2p]
    const int n0 = blockIdx.x * 8;
    const int t = threadIdx.x;
    const int len0 = stacklen[0];

    for (int tt = t; tt < 8 * 64; tt += 256) {
        int r = tt >> 6, d = tt & 63;
        int n = n0 + r;
        int s = (n >= len0) ? 1 : 0;
        float m1 = segstats[s * 128 + d],        r1 = segstats[s * 128 + 64 + d];
        float m2 = segstats[(2 + s) * 128 + d],  r2 = segstats[(2 + s) * 128 + 64 + d];
        float x1n = (y1[(size_t)n * DH + d] - m1) * r1;
        float x2n = (y2[(size_t)n * DH + d] - m2) * r2;
        xc[r][d] = x1n;
        sbuf[r][d] = x1n + x2n;
    }
    __syncthreads();

    // x2p[r][d] = sum_e sbuf[r][e] * w_midmini[d][e]
    for (int tt = t; tt < 8 * 64; tt += 256) {
        int r = tt >> 6, d = tt & 63;
        float a = 0.f;
        const float4* wmr = (const float4*)&w_midmini[(size_t)d * 64];
        const float4* sv = (const float4*)&sbuf[r][0];
        #pragma unroll
        for (int e4 = 0; e4 < 16; ++e4) {
            float4 w4 = wmr[e4], s4 = sv[e4];
            a += w4.x * s4.x + w4.y * s4.y + w4.z * s4.z + w4.w * s4.w;
        }
        xc[r][64 + d] = a;
    }
    __syncthreads();

    // outpre[n][j] = sum_i xc[r][i] * w_final[j][i]
    {
        const int j = t & 127;
        const int g = t >> 7;
        float o0 = 0.f, o1 = 0.f, o2 = 0.f, o3 = 0.f;
        const float4* wfr = (const float4*)&w_final[(size_t)j * 128];
        #pragma unroll 8
        for (int i4 = 0; i4 < 32; ++i4) {
            float4 wf = wfr[i4];
            float4 a0 = *(const float4*)&xc[g + 0][i4 * 4];
            float4 a1 = *(const float4*)&xc[g + 2][i4 * 4];
            float4 a2 = *(const float4*)&xc[g + 4][i4 * 4];
            float4 a3 = *(const float4*)&xc[g + 6][i4 * 4];
            o0 += wf.x * a0.x + wf.y * a0.y + wf.z * a0.z + wf.w * a0.w;
            o1 += wf.x * a1.x + wf.y * a1.y + wf.z * a1.z + wf.w * a1.w;
            o2 += wf.x * a2.x + wf.y * a2.y + wf.z * a2.z + wf.w * a2.w;
            o3 += wf.x * a3.x + wf.y * a3.y + wf.z * a3.z + wf.w * a3.w;
        }
        outpre[(size_t)(n0 + g + 0) * CH + j] = o0;
        outpre[(size_t)(n0 + g + 2) * CH + j] = o1;
        outpre[(size_t)(n0 + g + 4) * CH + j] = o2;
        outpre[(size_t)(n0 + g + 6) * CH + j] = o3;
    }
}

// ---------------- kernel 4: BN partial sums (atomic into zeroed ws) -----------
__global__ __launch_bounds__(256) void k_bnsum(const float* __restrict__ outpre,
                                               float* __restrict__ bnsum,
                                               float* __restrict__ bnsq)
{
    int j = threadIdx.x & 127, g = threadIdx.x >> 7;
    int b = blockIdx.x;   // 64 blocks
    float s = 0.f, q = 0.f;
    for (int r = b * 2 + g; r < NQ; r += 128) {
        float v = outpre[(size_t)r * CH + j];
        s += v; q += v * v;
    }
    __shared__ float ls[2][128], lq[2][128];
    ls[g][j] = s; lq[g][j] = q;
    __syncthreads();
    if (g == 0) {
        atomicAdd(&bnsum[j], s + ls[1][j]);
        atomicAdd(&bnsq[j], q + lq[1][j]);
    }
}

// ---------------- kernel 5: BN apply + relu ----------------------------------
__global__ __launch_bounds__(256) void k_bnapply(const float* __restrict__ outpre,
    const float* __restrict__ bnsum, const float* __restrict__ bnsq,
    const float* __restrict__ gamma, const float* __restrict__ beta,
    float* __restrict__ out)
{
    int e4 = blockIdx.x * 256 + threadIdx.x;
    if (e4 >= NQ * CH / 4) return;
    int j0 = (e4 * 4) & 127;
    float4 v = ((const float4*)outpre)[e4];
    float vv[4] = {v.x, v.y, v.z, v.w};
    float res[4];
    #pragma unroll
    for (int i = 0; i < 4; ++i) {
        int j = j0 + i;
        float mean = bnsum[j] * (1.0f / NQ);
        float var = bnsq[j] * (1.0f / NQ) - mean * mean;
        float rstd = rsqrtf(fmaxf(var, 0.f) + EPSN);
        float r = (vv[i] - mean) * rstd * gamma[j] + beta[j];
        res[i] = fmaxf(r, 0.f);
    }
    ((float4*)out)[e4] = make_float4(res[0], res[1], res[2], res[3]);
}

extern "C" void kernel_launch(void* const* d_in, const int* in_sizes, int n_in,
                              void* d_out, int out_size, void* d_ws, size_t ws_size,
                              hipStream_t stream) {
    const float* q_pts     = (const float*)d_in[0];
    const float* s_pts     = (const float*)d_in[1];
    const int*   inds      = (const int*)d_in[2];
    const float* x         = (const float*)d_in[3];
    const int*   stacklen  = (const int*)d_in[4];
    const float* kp_mini   = (const float*)d_in[5];
    const float* w_mini    = (const float*)d_in[6];
    const float* kp_mid    = (const float*)d_in[7];
    const float* w_mid     = (const float*)d_in[8];
    const float* w_midmini = (const float*)d_in[9];
    const float* w_final   = (const float*)d_in[10];
    const float* gamma     = (const float*)d_in[11];
    const float* beta      = (const float*)d_in[12];

    float* ws      = (float*)d_ws;
    float* rowsum  = ws + OFF_ROWSUM;
    float* y1      = ws + OFF_Y1;
    float* y2      = ws + OFF_Y2;
    float* segst   = ws + OFF_SEG;
    float* outpre  = ws + OFF_OUTPRE;
    float* bnsum   = ws + OFF_BNSUM;
    float* bnsq    = ws + OFF_BNSQ;

    hipMemsetAsync(bnsum, 0, 256 * sizeof(float), stream);

    k_rowsum<<<MS / 4, 256, 0, stream>>>(x, rowsum);
    k_kpconv<<<NQ / 4, 256, 0, stream>>>(q_pts, s_pts, inds, x, kp_mini, kp_mid,
                                         w_mini, w_mid, rowsum, y1, y2);
    k_segstats<<<4, 256, 0, stream>>>(y1, y2, stacklen, segst);
    k_tail<<<NQ / 8, 256, 0, stream>>>(y1, y2, segst, stacklen, w_midmini, w_final, outpre);
    k_bnsum<<<64, 256, 0, stream>>>(outpre, bnsum, bnsq);
    k_bnapply<<<(NQ * CH / 4 + 255) / 256, 256, 0, stream>>>(outpre, bnsum, bnsq,
                                                             gamma, beta, (float*)d_out);
}

// Round 2
// 497.450 us; speedup vs baseline: 2.3254x; 2.3254x over previous
//
#include <hip/hip_runtime.h>
#include <math.h>

#define NQ 20000
#define MS 20000
#define HN 32
#define CH 128
#define DH 64
#define KTOT 20
#define KMINI 7
#define EPSN 1e-5f

// workspace layout (in floats)
#define OFF_ROWSUM 0
#define OFF_Y1     20480
#define OFF_Y2     (OFF_Y1 + NQ*DH)
#define OFF_SEG    (OFF_Y2 + NQ*DH)           // segstats: 4*128 floats
#define OFF_SEGSUM (OFF_SEG + 512)            // 512 floats, zeroed each launch
#define OFF_BNSUM  (OFF_SEGSUM + 512)         // 128 floats, zeroed
#define OFF_BNSQ   (OFF_BNSUM + 128)          // 128 floats, zeroed
#define OFF_OUTPRE (OFF_BNSQ + 128)

// ---------------- kernel 0: per-row sum of x (density sign test) --------------
__global__ __launch_bounds__(256) void k_rowsum(const float* __restrict__ x,
                                                float* __restrict__ rowsum) {
    int row = blockIdx.x * 4 + (threadIdx.x >> 6);
    int lane = threadIdx.x & 63;
    if (row >= MS) return;
    double s = (double)x[row * CH + lane] + (double)x[row * CH + 64 + lane];
    #pragma unroll
    for (int off = 32; off > 0; off >>= 1) s += __shfl_down(s, off, 64);
    if (lane == 0) rowsum[row] = (float)s;
}

// ---------------- kernel 1: fused dual KPConv (mini + mid), 4 rows/block ------
__global__ __launch_bounds__(256) void k_kpconv(
    const float* __restrict__ q_pts, const float* __restrict__ s_pts,
    const int* __restrict__ inds, const float* __restrict__ x,
    const float* __restrict__ kp_mini, const float* __restrict__ kp_mid,
    const float* __restrict__ w_mini, const float* __restrict__ w_mid,
    const float* __restrict__ rowsum,
    float* __restrict__ y1, float* __restrict__ y2)
{
    __shared__ __align__(16) float kpts[KTOT][3];
    __shared__ __align__(16) float nb[128][3];
    __shared__ int   nidx[128];
    __shared__ int   vcnt[4];
    __shared__ float winv[4];
    __shared__ __align__(16) float wts[4][HN][KTOT];   // per (row,h,k) influence * 1/n_num
    __shared__ __align__(16) float wt[KTOT][CH][4];    // weighted[k][c][row]
    __shared__ __align__(16) float part[128][4];

    const int t = threadIdx.x;
    const int n0 = blockIdx.x * 4;

    if (t < KTOT * 3) {
        int k = t / 3, j = t % 3;
        kpts[k][j] = (k < KMINI) ? kp_mini[k * 3 + j] : kp_mid[(k - KMINI) * 3 + j];
    }
    if (t < 4) vcnt[t] = 0;
    __syncthreads();

    // neighbor vectors + validity count
    if (t < 128) {
        int r = t >> 5, h = t & 31;
        int n = n0 + r;
        int idx = inds[n * HN + h];
        nidx[t] = idx;
        float qx = q_pts[n * 3 + 0], qy = q_pts[n * 3 + 1], qz = q_pts[n * 3 + 2];
        nb[t][0] = s_pts[idx * 3 + 0] - qx;
        nb[t][1] = s_pts[idx * 3 + 1] - qy;
        nb[t][2] = s_pts[idx * 3 + 2] - qz;
        if (rowsum[idx] > 0.0f) atomicAdd(&vcnt[r], 1);
    }
    __syncthreads();
    if (t < 4) winv[t] = 1.0f / (float)max(vcnt[t], 1);
    __syncthreads();

    // KP influences: 4*32*20 = 2560 values
    for (int tt = t; tt < 4 * HN * KTOT; tt += 256) {
        int r = tt / (HN * KTOT);
        int rem = tt % (HN * KTOT);
        int h = rem / KTOT, k = rem % KTOT;
        float dx = nb[r * HN + h][0] - kpts[k][0];
        float dy = nb[r * HN + h][1] - kpts[k][1];
        float dz = nb[r * HN + h][2] - kpts[k][2];
        float sq = dx * dx + dy * dy + dz * dz;
        float dist = sqrtf(fmaxf(sq, 1e-12f));
        float w = fmaxf(1.0f - dist * (1.0f / 0.6f), 0.0f);
        wts[r][h][k] = w * winv[r];
    }
    __syncthreads();

    // accumulate weighted[k][c] over h; group g owns rows {g, g+2}
    {
        const int g = t >> 7;
        const int c = t & 127;
        for (int rr = 0; rr < 2; ++rr) {
            const int r = g + rr * 2;
            float acc[KTOT];
            #pragma unroll
            for (int k = 0; k < KTOT; ++k) acc[k] = 0.0f;
            for (int h = 0; h < HN; ++h) {
                int idx = nidx[r * HN + h];
                float xv = x[(size_t)idx * CH + c];
                const float4* wp = (const float4*)&wts[r][h][0];
                float4 wa = wp[0], wb = wp[1], wc = wp[2], wd = wp[3], we = wp[4];
                acc[0]  += wa.x * xv; acc[1]  += wa.y * xv; acc[2]  += wa.z * xv; acc[3]  += wa.w * xv;
                acc[4]  += wb.x * xv; acc[5]  += wb.y * xv; acc[6]  += wb.z * xv; acc[7]  += wb.w * xv;
                acc[8]  += wc.x * xv; acc[9]  += wc.y * xv; acc[10] += wc.z * xv; acc[11] += wc.w * xv;
                acc[12] += wd.x * xv; acc[13] += wd.y * xv; acc[14] += wd.z * xv; acc[15] += wd.w * xv;
                acc[16] += we.x * xv; acc[17] += we.y * xv; acc[18] += we.z * xv; acc[19] += we.w * xv;
            }
            #pragma unroll
            for (int k = 0; k < KTOT; ++k) wt[k][c][r] = acc[k];
        }
    }
    __syncthreads();

    // output GEMM: out[r][d] = sum_{k,c} wt[k][c][r] * W[k][c][d]
    {
        const int d = t & 127;
        const int half = t >> 7;
        const int c0 = half * 64;
        float o0 = 0.f, o1 = 0.f, o2 = 0.f, o3 = 0.f;
        if (d < DH) {
            for (int k = 0; k < KMINI; ++k) {
                const float* wp = &w_mini[((size_t)k * CH + c0) * DH + d];
                for (int c = c0; c < c0 + 64; ++c) {
                    float wv = *wp; wp += DH;
                    const float4 wtv = *(const float4*)&wt[k][c][0];
                    o0 += wv * wtv.x; o1 += wv * wtv.y; o2 += wv * wtv.z; o3 += wv * wtv.w;
                }
            }
        } else {
            const int dd = d - DH;
            for (int k = KMINI; k < KTOT; ++k) {
                const float* wp = &w_mid[((size_t)(k - KMINI) * CH + c0) * DH + dd];
                for (int c = c0; c < c0 + 64; ++c) {
                    float wv = *wp; wp += DH;
                    const float4 wtv = *(const float4*)&wt[k][c][0];
                    o0 += wv * wtv.x; o1 += wv * wtv.y; o2 += wv * wtv.z; o3 += wv * wtv.w;
                }
            }
        }
        if (half == 1) { part[d][0] = o0; part[d][1] = o1; part[d][2] = o2; part[d][3] = o3; }
        __syncthreads();
        if (half == 0) {
            o0 += part[d][0]; o1 += part[d][1]; o2 += part[d][2]; o3 += part[d][3];
            if (d < DH) {
                y1[(size_t)(n0 + 0) * DH + d] = o0;
                y1[(size_t)(n0 + 1) * DH + d] = o1;
                y1[(size_t)(n0 + 2) * DH + d] = o2;
                y1[(size_t)(n0 + 3) * DH + d] = o3;
            } else {
                const int dd = d - DH;
                y2[(size_t)(n0 + 0) * DH + dd] = o0;
                y2[(size_t)(n0 + 1) * DH + dd] = o1;
                y2[(size_t)(n0 + 2) * DH + dd] = o2;
                y2[(size_t)(n0 + 3) * DH + dd] = o3;
            }
        }
    }
}

// -------- kernel 2a: parallel per-segment partial sums (atomic into ws) -------
// segsum layout: j = ((tensor*2 + seg)*2 + isq), value at segsum[j*64 + ch]
__global__ __launch_bounds__(256) void k_segpart(
    const float* __restrict__ y1, const float* __restrict__ y2,
    const int* __restrict__ stacklen, float* __restrict__ segsum)
{
    const int t = threadIdx.x;
    const int ch = t & 63, grp = t >> 6;
    const int len0 = stacklen[0];
    float a0 = 0.f, a1 = 0.f, a2 = 0.f, a3 = 0.f;   // y1: sum0, sq0, sum1, sq1
    float b0 = 0.f, b1 = 0.f, b2 = 0.f, b3 = 0.f;   // y2: sum0, sq0, sum1, sq1
    for (int r = blockIdx.x * 4 + grp; r < NQ; r += 256 * 4) {
        float v1 = y1[(size_t)r * DH + ch];
        float v2 = y2[(size_t)r * DH + ch];
        bool in1 = (r >= len0);
        float m0 = in1 ? 0.f : 1.f, m1 = 1.f - m0;
        a0 += m0 * v1; a1 += m0 * v1 * v1; a2 += m1 * v1; a3 += m1 * v1 * v1;
        b0 += m0 * v2; b1 += m0 * v2 * v2; b2 += m1 * v2; b3 += m1 * v2 * v2;
    }
    __shared__ float red[4][8][64];
    red[grp][0][ch] = a0; red[grp][1][ch] = a1; red[grp][2][ch] = a2; red[grp][3][ch] = a3;
    red[grp][4][ch] = b0; red[grp][5][ch] = b1; red[grp][6][ch] = b2; red[grp][7][ch] = b3;
    __syncthreads();
    for (int tt = t; tt < 512; tt += 256) {
        int j = tt >> 6, c = tt & 63;
        float s = red[0][j][c] + red[1][j][c] + red[2][j][c] + red[3][j][c];
        atomicAdd(&segsum[j * 64 + c], s);
    }
}

// -------- kernel 2b: finalize mean/rstd ---------------------------------------
__global__ __launch_bounds__(256) void k_segfin(
    const float* __restrict__ segsum, const int* __restrict__ stacklen,
    float* __restrict__ segstats)
{
    const int t = threadIdx.x;          // 256 = 4 combos * 64 ch
    const int combo = t >> 6;           // tensor*2 + seg
    const int ch = t & 63;
    const int len0 = stacklen[0];
    const int s = combo & 1;
    float cnt = (float)max(s ? (NQ - len0) : len0, 1);
    float S = segsum[(combo * 2 + 0) * 64 + ch];
    float Q = segsum[(combo * 2 + 1) * 64 + ch];
    float mean = S / cnt;
    float var = Q / cnt - mean * mean;
    float rstd = rsqrtf(fmaxf(var, 0.f) + EPSN);
    segstats[combo * 128 + ch] = mean;
    segstats[combo * 128 + 64 + ch] = rstd;
}

// ------- kernel 3: segment-norm + midmini linear + concat + final linear ------
__global__ __launch_bounds__(256) void k_tail(
    const float* __restrict__ y1, const float* __restrict__ y2,
    const float* __restrict__ segstats, const int* __restrict__ stacklen,
    const float* __restrict__ w_midmini, const float* __restrict__ w_final,
    float* __restrict__ outpre)
{
    __shared__ __align__(16) float sbuf[8][64];    // x1n + x2n
    __shared__ __align__(16) float xc[8][128];     // [x1n | x2p]
    const int n0 = blockIdx.x * 8;
    const int t = threadIdx.x;
    const int len0 = stacklen[0];

    for (int tt = t; tt < 8 * 64; tt += 256) {
        int r = tt >> 6, d = tt & 63;
        int n = n0 + r;
        int s = (n >= len0) ? 1 : 0;
        float m1 = segstats[s * 128 + d],        r1 = segstats[s * 128 + 64 + d];
        float m2 = segstats[(2 + s) * 128 + d],  r2 = segstats[(2 + s) * 128 + 64 + d];
        float x1n = (y1[(size_t)n * DH + d] - m1) * r1;
        float x2n = (y2[(size_t)n * DH + d] - m2) * r2;
        xc[r][d] = x1n;
        sbuf[r][d] = x1n + x2n;
    }
    __syncthreads();

    // x2p[r][d] = sum_e sbuf[r][e] * w_midmini[d][e]
    for (int tt = t; tt < 8 * 64; tt += 256) {
        int r = tt >> 6, d = tt & 63;
        float a = 0.f;
        const float4* wmr = (const float4*)&w_midmini[(size_t)d * 64];
        const float4* sv = (const float4*)&sbuf[r][0];
        #pragma unroll
        for (int e4 = 0; e4 < 16; ++e4) {
            float4 w4 = wmr[e4], s4 = sv[e4];
            a += w4.x * s4.x + w4.y * s4.y + w4.z * s4.z + w4.w * s4.w;
        }
        xc[r][64 + d] = a;
    }
    __syncthreads();

    // outpre[n][j] = sum_i xc[r][i] * w_final[j][i]
    {
        const int j = t & 127;
        const int g = t >> 7;
        float o0 = 0.f, o1 = 0.f, o2 = 0.f, o3 = 0.f;
        const float4* wfr = (const float4*)&w_final[(size_t)j * 128];
        #pragma unroll 8
        for (int i4 = 0; i4 < 32; ++i4) {
            float4 wf = wfr[i4];
            float4 a0 = *(const float4*)&xc[g + 0][i4 * 4];
            float4 a1 = *(const float4*)&xc[g + 2][i4 * 4];
            float4 a2 = *(const float4*)&xc[g + 4][i4 * 4];
            float4 a3 = *(const float4*)&xc[g + 6][i4 * 4];
            o0 += wf.x * a0.x + wf.y * a0.y + wf.z * a0.z + wf.w * a0.w;
            o1 += wf.x * a1.x + wf.y * a1.y + wf.z * a1.z + wf.w * a1.w;
            o2 += wf.x * a2.x + wf.y * a2.y + wf.z * a2.z + wf.w * a2.w;
            o3 += wf.x * a3.x + wf.y * a3.y + wf.z * a3.z + wf.w * a3.w;
        }
        outpre[(size_t)(n0 + g + 0) * CH + j] = o0;
        outpre[(size_t)(n0 + g + 2) * CH + j] = o1;
        outpre[(size_t)(n0 + g + 4) * CH + j] = o2;
        outpre[(size_t)(n0 + g + 6) * CH + j] = o3;
    }
}

// ---------------- kernel 4: BN partial sums (atomic into zeroed ws) -----------
__global__ __launch_bounds__(256) void k_bnsum(const float* __restrict__ outpre,
                                               float* __restrict__ bnsum,
                                               float* __restrict__ bnsq)
{
    int j = threadIdx.x & 127, g = threadIdx.x >> 7;
    int b = blockIdx.x;   // 64 blocks
    float s = 0.f, q = 0.f;
    for (int r = b * 2 + g; r < NQ; r += 128) {
        float v = outpre[(size_t)r * CH + j];
        s += v; q += v * v;
    }
    __shared__ float ls[2][128], lq[2][128];
    ls[g][j] = s; lq[g][j] = q;
    __syncthreads();
    if (g == 0) {
        atomicAdd(&bnsum[j], s + ls[1][j]);
        atomicAdd(&bnsq[j], q + lq[1][j]);
    }
}

// ---------------- kernel 5: BN apply + relu ----------------------------------
__global__ __launch_bounds__(256) void k_bnapply(const float* __restrict__ outpre,
    const float* __restrict__ bnsum, const float* __restrict__ bnsq,
    const float* __restrict__ gamma, const float* __restrict__ beta,
    float* __restrict__ out)
{
    int e4 = blockIdx.x * 256 + threadIdx.x;
    if (e4 >= NQ * CH / 4) return;
    int j0 = (e4 * 4) & 127;
    float4 v = ((const float4*)outpre)[e4];
    float vv[4] = {v.x, v.y, v.z, v.w};
    float res[4];
    #pragma unroll
    for (int i = 0; i < 4; ++i) {
        int j = j0 + i;
        float mean = bnsum[j] * (1.0f / NQ);
        float var = bnsq[j] * (1.0f / NQ) - mean * mean;
        float rstd = rsqrtf(fmaxf(var, 0.f) + EPSN);
        float r = (vv[i] - mean) * rstd * gamma[j] + beta[j];
        res[i] = fmaxf(r, 0.f);
    }
    ((float4*)out)[e4] = make_float4(res[0], res[1], res[2], res[3]);
}

extern "C" void kernel_launch(void* const* d_in, const int* in_sizes, int n_in,
                              void* d_out, int out_size, void* d_ws, size_t ws_size,
                              hipStream_t stream) {
    const float* q_pts     = (const float*)d_in[0];
    const float* s_pts     = (const float*)d_in[1];
    const int*   inds      = (const int*)d_in[2];
    const float* x         = (const float*)d_in[3];
    const int*   stacklen  = (const int*)d_in[4];
    const float* kp_mini   = (const float*)d_in[5];
    const float* w_mini    = (const float*)d_in[6];
    const float* kp_mid    = (const float*)d_in[7];
    const float* w_mid     = (const float*)d_in[8];
    const float* w_midmini = (const float*)d_in[9];
    const float* w_final   = (const float*)d_in[10];
    const float* gamma     = (const float*)d_in[11];
    const float* beta      = (const float*)d_in[12];

    float* ws      = (float*)d_ws;
    float* rowsum  = ws + OFF_ROWSUM;
    float* y1      = ws + OFF_Y1;
    float* y2      = ws + OFF_Y2;
    float* segst   = ws + OFF_SEG;
    float* segsum  = ws + OFF_SEGSUM;
    float* bnsum   = ws + OFF_BNSUM;
    float* bnsq    = ws + OFF_BNSQ;
    float* outpre  = ws + OFF_OUTPRE;

    // zero segsum (512) + bnsum (128) + bnsq (128) in one shot
    hipMemsetAsync(segsum, 0, (512 + 256) * sizeof(float), stream);

    k_rowsum<<<MS / 4, 256, 0, stream>>>(x, rowsum);
    k_kpconv<<<NQ / 4, 256, 0, stream>>>(q_pts, s_pts, inds, x, kp_mini, kp_mid,
                                         w_mini, w_mid, rowsum, y1, y2);
    k_segpart<<<256, 256, 0, stream>>>(y1, y2, stacklen, segsum);
    k_segfin<<<1, 256, 0, stream>>>(segsum, stacklen, segst);
    k_tail<<<NQ / 8, 256, 0, stream>>>(y1, y2, segst, stacklen, w_midmini, w_final, outpre);
    k_bnsum<<<64, 256, 0, stream>>>(outpre, bnsum, bnsq);
    k_bnapply<<<(NQ * CH / 4 + 255) / 256, 256, 0, stream>>>(outpre, bnsum, bnsq,
                                                             gamma, beta, (float*)d_out);
}

// Round 3
// 376.909 us; speedup vs baseline: 3.0692x; 1.3198x over previous
//
#include <hip/hip_runtime.h>
#include <math.h>

#define NQ 20000
#define MS 20000
#define HN 32
#define CH 128
#define DH 64
#define KTOT 20
#define KMINI 7
#define EPSN 1e-5f
#define KDIM 2560            // KTOT*CH
#define NKT 80               // KDIM/32
#define KT_SPLIT 28          // kt < 28 -> k<7 (y1 cols), else y2 cols

// workspace layout (in float units)
#define OFF_ROWSUM 0
#define OFF_Y1     20480
#define OFF_Y2     (OFF_Y1 + NQ*DH)
#define OFF_SEG    (OFF_Y2 + NQ*DH)           // 512
#define OFF_SEGSUM (OFF_SEG + 512)            // 512, zeroed
#define OFF_BNSUM  (OFF_SEGSUM + 512)         // 128, zeroed
#define OFF_BNSQ   (OFF_BNSUM + 128)          // 128, zeroed
#define OFF_OUTPRE (OFF_BNSQ + 128)           // NQ*CH
#define OFF_WSWZ   (OFF_OUTPRE + NQ*CH)       // 327680 ushort = 163840 floats
#define OFF_P      (OFF_WSWZ + 163840)        // NQ*KDIM ushort = 25600000 floats
#define TOT_FLOATS (OFF_P + NQ*KDIM/2)

typedef __attribute__((ext_vector_type(8))) short bf16x8;
typedef __attribute__((ext_vector_type(4))) float f32x4;

static __device__ inline unsigned short f2bf(float f) {
    unsigned int u = __float_as_uint(f);
    unsigned int r = (u + 0x7fffu + ((u >> 16) & 1u)) >> 16;
    return (unsigned short)r;
}

// ---------------- kernel 0: per-row sum of x (density sign test) --------------
__global__ __launch_bounds__(256) void k_rowsum(const float* __restrict__ x,
                                                float* __restrict__ rowsum) {
    int row = blockIdx.x * 4 + (threadIdx.x >> 6);
    int lane = threadIdx.x & 63;
    if (row >= MS) return;
    double s = (double)x[row * CH + lane] + (double)x[row * CH + 64 + lane];
    #pragma unroll
    for (int off = 32; off > 0; off >>= 1) s += __shfl_down(s, off, 64);
    if (lane == 0) rowsum[row] = (float)s;
}

// ---------------- kernel G: gather + influence -> P bf16 [n][k*128+c] ---------
__global__ __launch_bounds__(256) void k_gather(
    const float* __restrict__ q_pts, const float* __restrict__ s_pts,
    const int* __restrict__ inds, const float* __restrict__ x,
    const float* __restrict__ kp_mini, const float* __restrict__ kp_mid,
    const float* __restrict__ rowsum,
    unsigned short* __restrict__ P)
{
    __shared__ __align__(16) float kpts[KTOT][3];
    __shared__ __align__(16) float nb[128][3];
    __shared__ int   nidx[128];
    __shared__ int   vcnt[4];
    __shared__ float winv[4];
    __shared__ __align__(16) float wts[4][HN][KTOT];

    const int t = threadIdx.x;
    const int n0 = blockIdx.x * 4;

    if (t < KTOT * 3) {
        int k = t / 3, j = t % 3;
        kpts[k][j] = (k < KMINI) ? kp_mini[k * 3 + j] : kp_mid[(k - KMINI) * 3 + j];
    }
    if (t < 4) vcnt[t] = 0;
    __syncthreads();

    if (t < 128) {
        int r = t >> 5, h = t & 31;
        int n = n0 + r;
        int idx = inds[n * HN + h];
        nidx[t] = idx;
        float qx = q_pts[n * 3 + 0], qy = q_pts[n * 3 + 1], qz = q_pts[n * 3 + 2];
        nb[t][0] = s_pts[idx * 3 + 0] - qx;
        nb[t][1] = s_pts[idx * 3 + 1] - qy;
        nb[t][2] = s_pts[idx * 3 + 2] - qz;
        if (rowsum[idx] > 0.0f) atomicAdd(&vcnt[r], 1);
    }
    __syncthreads();
    if (t < 4) winv[t] = 1.0f / (float)max(vcnt[t], 1);
    __syncthreads();

    for (int tt = t; tt < 4 * HN * KTOT; tt += 256) {
        int r = tt / (HN * KTOT);
        int rem = tt % (HN * KTOT);
        int h = rem / KTOT, k = rem % KTOT;
        float dx = nb[r * HN + h][0] - kpts[k][0];
        float dy = nb[r * HN + h][1] - kpts[k][1];
        float dz = nb[r * HN + h][2] - kpts[k][2];
        float sq = dx * dx + dy * dy + dz * dz;
        float dist = sqrtf(fmaxf(sq, 1e-12f));
        float w = fmaxf(1.0f - dist * (1.0f / 0.6f), 0.0f);
        wts[r][h][k] = w * winv[r];
    }
    __syncthreads();

    // accumulate P[r][k*128+c] over h; group g owns rows {g, g+2}
    const int g = t >> 7;
    const int c = t & 127;
    for (int rr = 0; rr < 2; ++rr) {
        const int r = g + rr * 2;
        float acc[KTOT];
        #pragma unroll
        for (int k = 0; k < KTOT; ++k) acc[k] = 0.0f;
        for (int h = 0; h < HN; ++h) {
            int idx = nidx[r * HN + h];
            float xv = x[(size_t)idx * CH + c];
            const float4* wp = (const float4*)&wts[r][h][0];
            float4 wa = wp[0], wb = wp[1], wc = wp[2], wd = wp[3], we = wp[4];
            acc[0]  += wa.x * xv; acc[1]  += wa.y * xv; acc[2]  += wa.z * xv; acc[3]  += wa.w * xv;
            acc[4]  += wb.x * xv; acc[5]  += wb.y * xv; acc[6]  += wb.z * xv; acc[7]  += wb.w * xv;
            acc[8]  += wc.x * xv; acc[9]  += wc.y * xv; acc[10] += wc.z * xv; acc[11] += wc.w * xv;
            acc[12] += wd.x * xv; acc[13] += wd.y * xv; acc[14] += wd.z * xv; acc[15] += wd.w * xv;
            acc[16] += we.x * xv; acc[17] += we.y * xv; acc[18] += we.z * xv; acc[19] += we.w * xv;
        }
        unsigned short* prow = P + (size_t)(n0 + r) * KDIM + c;
        #pragma unroll
        for (int k = 0; k < KTOT; ++k) prow[k * CH] = f2bf(acc[k]);
    }
}

// ---------------- kernel W: swizzle weights into MFMA B-fragment order --------
// wswz[((kt*8+nt)*64 + lane)*8 + j] = W[kt*32 + (lane>>4)*8 + j][nt*16 + (lane&15)]
__global__ __launch_bounds__(256) void k_wprep(
    const float* __restrict__ w_mini, const float* __restrict__ w_mid,
    unsigned short* __restrict__ wswz)
{
    int gid = blockIdx.x * 256 + threadIdx.x;
    if (gid >= NKT * 8 * 512) return;
    int j = gid & 7;
    int l = (gid >> 3) & 63;
    int ntkt = gid >> 9;
    int nt = ntkt & 7;
    int kt = ntkt >> 3;
    int kg = kt * 32 + ((l >> 4) << 3) + j;   // 0..2559
    int d  = nt * 16 + (l & 15);              // 0..127
    int k = kg >> 7, c = kg & 127;
    float v = 0.0f;
    if (k < KMINI && d < DH)       v = w_mini[((size_t)k * CH + c) * DH + d];
    else if (k >= KMINI && d >= DH) v = w_mid[((size_t)(k - KMINI) * CH + c) * DH + (d - DH)];
    wswz[gid] = f2bf(v);
}

// ---------------- kernel M: block-diagonal MFMA GEMM -> y1, y2 ----------------
__global__ __launch_bounds__(256) void k_mfma(
    const unsigned short* __restrict__ P, const unsigned short* __restrict__ wswz,
    float* __restrict__ y1, float* __restrict__ y2)
{
    const int l = threadIdx.x & 63;
    const int w = threadIdx.x >> 6;
    const int mt = blockIdx.x * 4 + w;
    if (mt >= NQ / 16) return;

    f32x4 acc[8];
    #pragma unroll
    for (int i = 0; i < 8; ++i) acc[i] = (f32x4){0.f, 0.f, 0.f, 0.f};

    const unsigned short* arow = P + (size_t)(mt * 16 + (l & 15)) * KDIM + ((l >> 4) << 3);
    const unsigned short* bbase = wswz + l * 8;

    for (int kt = 0; kt < NKT; ++kt) {
        bf16x8 a = *(const bf16x8*)(arow + kt * 32);
        const int ntb = (kt < KT_SPLIT) ? 0 : 4;
        #pragma unroll
        for (int q = 0; q < 4; ++q) {
            int nt = ntb + q;
            bf16x8 b = *(const bf16x8*)(bbase + (size_t)(kt * 8 + nt) * 512);
            acc[nt] = __builtin_amdgcn_mfma_f32_16x16x32_bf16(a, b, acc[nt], 0, 0, 0);
        }
    }

    const int rbase = mt * 16 + ((l >> 4) << 2);
    const int c0 = l & 15;
    #pragma unroll
    for (int nt = 0; nt < 8; ++nt) {
        int col = nt * 16 + c0;
        #pragma unroll
        for (int reg = 0; reg < 4; ++reg) {
            int row = rbase + reg;
            float v = acc[nt][reg];
            if (col < DH) y1[(size_t)row * DH + col] = v;
            else          y2[(size_t)row * DH + (col - DH)] = v;
        }
    }
}

// ---------------- FALLBACK: R1 fused kpconv (if ws too small) -----------------
__global__ __launch_bounds__(256) void k_kpconv(
    const float* __restrict__ q_pts, const float* __restrict__ s_pts,
    const int* __restrict__ inds, const float* __restrict__ x,
    const float* __restrict__ kp_mini, const float* __restrict__ kp_mid,
    const float* __restrict__ w_mini, const float* __restrict__ w_mid,
    const float* __restrict__ rowsum,
    float* __restrict__ y1, float* __restrict__ y2)
{
    __shared__ __align__(16) float kpts[KTOT][3];
    __shared__ __align__(16) float nb[128][3];
    __shared__ int   nidx[128];
    __shared__ int   vcnt[4];
    __shared__ float winv[4];
    __shared__ __align__(16) float wts[4][HN][KTOT];
    __shared__ __align__(16) float wt[KTOT][CH][4];
    __shared__ __align__(16) float part[128][4];

    const int t = threadIdx.x;
    const int n0 = blockIdx.x * 4;

    if (t < KTOT * 3) {
        int k = t / 3, j = t % 3;
        kpts[k][j] = (k < KMINI) ? kp_mini[k * 3 + j] : kp_mid[(k - KMINI) * 3 + j];
    }
    if (t < 4) vcnt[t] = 0;
    __syncthreads();

    if (t < 128) {
        int r = t >> 5, h = t & 31;
        int n = n0 + r;
        int idx = inds[n * HN + h];
        nidx[t] = idx;
        float qx = q_pts[n * 3 + 0], qy = q_pts[n * 3 + 1], qz = q_pts[n * 3 + 2];
        nb[t][0] = s_pts[idx * 3 + 0] - qx;
        nb[t][1] = s_pts[idx * 3 + 1] - qy;
        nb[t][2] = s_pts[idx * 3 + 2] - qz;
        if (rowsum[idx] > 0.0f) atomicAdd(&vcnt[r], 1);
    }
    __syncthreads();
    if (t < 4) winv[t] = 1.0f / (float)max(vcnt[t], 1);
    __syncthreads();

    for (int tt = t; tt < 4 * HN * KTOT; tt += 256) {
        int r = tt / (HN * KTOT);
        int rem = tt % (HN * KTOT);
        int h = rem / KTOT, k = rem % KTOT;
        float dx = nb[r * HN + h][0] - kpts[k][0];
        float dy = nb[r * HN + h][1] - kpts[k][1];
        float dz = nb[r * HN + h][2] - kpts[k][2];
        float sq = dx * dx + dy * dy + dz * dz;
        float dist = sqrtf(fmaxf(sq, 1e-12f));
        float w = fmaxf(1.0f - dist * (1.0f / 0.6f), 0.0f);
        wts[r][h][k] = w * winv[r];
    }
    __syncthreads();

    {
        const int g = t >> 7;
        const int c = t & 127;
        for (int rr = 0; rr < 2; ++rr) {
            const int r = g + rr * 2;
            float acc[KTOT];
            #pragma unroll
            for (int k = 0; k < KTOT; ++k) acc[k] = 0.0f;
            for (int h = 0; h < HN; ++h) {
                int idx = nidx[r * HN + h];
                float xv = x[(size_t)idx * CH + c];
                const float4* wp = (const float4*)&wts[r][h][0];
                float4 wa = wp[0], wb = wp[1], wc = wp[2], wd = wp[3], we = wp[4];
                acc[0]  += wa.x * xv; acc[1]  += wa.y * xv; acc[2]  += wa.z * xv; acc[3]  += wa.w * xv;
                acc[4]  += wb.x * xv; acc[5]  += wb.y * xv; acc[6]  += wb.z * xv; acc[7]  += wb.w * xv;
                acc[8]  += wc.x * xv; acc[9]  += wc.y * xv; acc[10] += wc.z * xv; acc[11] += wc.w * xv;
                acc[12] += wd.x * xv; acc[13] += wd.y * xv; acc[14] += wd.z * xv; acc[15] += wd.w * xv;
                acc[16] += we.x * xv; acc[17] += we.y * xv; acc[18] += we.z * xv; acc[19] += we.w * xv;
            }
            #pragma unroll
            for (int k = 0; k < KTOT; ++k) wt[k][c][r] = acc[k];
        }
    }
    __syncthreads();

    {
        const int d = t & 127;
        const int half = t >> 7;
        const int c0 = half * 64;
        float o0 = 0.f, o1 = 0.f, o2 = 0.f, o3 = 0.f;
        if (d < DH) {
            for (int k = 0; k < KMINI; ++k) {
                const float* wp = &w_mini[((size_t)k * CH + c0) * DH + d];
                for (int c = c0; c < c0 + 64; ++c) {
                    float wv = *wp; wp += DH;
                    const float4 wtv = *(const float4*)&wt[k][c][0];
                    o0 += wv * wtv.x; o1 += wv * wtv.y; o2 += wv * wtv.z; o3 += wv * wtv.w;
                }
            }
        } else {
            const int dd = d - DH;
            for (int k = KMINI; k < KTOT; ++k) {
                const float* wp = &w_mid[((size_t)(k - KMINI) * CH + c0) * DH + dd];
                for (int c = c0; c < c0 + 64; ++c) {
                    float wv = *wp; wp += DH;
                    const float4 wtv = *(const float4*)&wt[k][c][0];
                    o0 += wv * wtv.x; o1 += wv * wtv.y; o2 += wv * wtv.z; o3 += wv * wtv.w;
                }
            }
        }
        if (half == 1) { part[d][0] = o0; part[d][1] = o1; part[d][2] = o2; part[d][3] = o3; }
        __syncthreads();
        if (half == 0) {
            o0 += part[d][0]; o1 += part[d][1]; o2 += part[d][2]; o3 += part[d][3];
            if (d < DH) {
                y1[(size_t)(n0 + 0) * DH + d] = o0;
                y1[(size_t)(n0 + 1) * DH + d] = o1;
                y1[(size_t)(n0 + 2) * DH + d] = o2;
                y1[(size_t)(n0 + 3) * DH + d] = o3;
            } else {
                const int dd = d - DH;
                y2[(size_t)(n0 + 0) * DH + dd] = o0;
                y2[(size_t)(n0 + 1) * DH + dd] = o1;
                y2[(size_t)(n0 + 2) * DH + dd] = o2;
                y2[(size_t)(n0 + 3) * DH + dd] = o3;
            }
        }
    }
}

// -------- kernel 2a: parallel per-segment partial sums ------------------------
__global__ __launch_bounds__(256) void k_segpart(
    const float* __restrict__ y1, const float* __restrict__ y2,
    const int* __restrict__ stacklen, float* __restrict__ segsum)
{
    const int t = threadIdx.x;
    const int ch = t & 63, grp = t >> 6;
    const int len0 = stacklen[0];
    float a0 = 0.f, a1 = 0.f, a2 = 0.f, a3 = 0.f;
    float b0 = 0.f, b1 = 0.f, b2 = 0.f, b3 = 0.f;
    for (int r = blockIdx.x * 4 + grp; r < NQ; r += 256 * 4) {
        float v1 = y1[(size_t)r * DH + ch];
        float v2 = y2[(size_t)r * DH + ch];
        bool in1 = (r >= len0);
        float m0 = in1 ? 0.f : 1.f, m1 = 1.f - m0;
        a0 += m0 * v1; a1 += m0 * v1 * v1; a2 += m1 * v1; a3 += m1 * v1 * v1;
        b0 += m0 * v2; b1 += m0 * v2 * v2; b2 += m1 * v2; b3 += m1 * v2 * v2;
    }
    __shared__ float red[4][8][64];
    red[grp][0][ch] = a0; red[grp][1][ch] = a1; red[grp][2][ch] = a2; red[grp][3][ch] = a3;
    red[grp][4][ch] = b0; red[grp][5][ch] = b1; red[grp][6][ch] = b2; red[grp][7][ch] = b3;
    __syncthreads();
    for (int tt = t; tt < 512; tt += 256) {
        int j = tt >> 6, c = tt & 63;
        float s = red[0][j][c] + red[1][j][c] + red[2][j][c] + red[3][j][c];
        atomicAdd(&segsum[j * 64 + c], s);
    }
}

// -------- kernel 2b: finalize mean/rstd ---------------------------------------
__global__ __launch_bounds__(256) void k_segfin(
    const float* __restrict__ segsum, const int* __restrict__ stacklen,
    float* __restrict__ segstats)
{
    const int t = threadIdx.x;
    const int combo = t >> 6;
    const int ch = t & 63;
    const int len0 = stacklen[0];
    const int s = combo & 1;
    float cnt = (float)max(s ? (NQ - len0) : len0, 1);
    float S = segsum[(combo * 2 + 0) * 64 + ch];
    float Q = segsum[(combo * 2 + 1) * 64 + ch];
    float mean = S / cnt;
    float var = Q / cnt - mean * mean;
    float rstd = rsqrtf(fmaxf(var, 0.f) + EPSN);
    segstats[combo * 128 + ch] = mean;
    segstats[combo * 128 + 64 + ch] = rstd;
}

// ------- kernel 3: segment-norm + midmini linear + concat + final linear ------
__global__ __launch_bounds__(256) void k_tail(
    const float* __restrict__ y1, const float* __restrict__ y2,
    const float* __restrict__ segstats, const int* __restrict__ stacklen,
    const float* __restrict__ w_midmini, const float* __restrict__ w_final,
    float* __restrict__ outpre)
{
    __shared__ __align__(16) float sbuf[8][64];
    __shared__ __align__(16) float xc[8][128];
    const int n0 = blockIdx.x * 8;
    const int t = threadIdx.x;
    const int len0 = stacklen[0];

    for (int tt = t; tt < 8 * 64; tt += 256) {
        int r = tt >> 6, d = tt & 63;
        int n = n0 + r;
        int s = (n >= len0) ? 1 : 0;
        float m1 = segstats[s * 128 + d],        r1 = segstats[s * 128 + 64 + d];
        float m2 = segstats[(2 + s) * 128 + d],  r2 = segstats[(2 + s) * 128 + 64 + d];
        float x1n = (y1[(size_t)n * DH + d] - m1) * r1;
        float x2n = (y2[(size_t)n * DH + d] - m2) * r2;
        xc[r][d] = x1n;
        sbuf[r][d] = x1n + x2n;
    }
    __syncthreads();

    for (int tt = t; tt < 8 * 64; tt += 256) {
        int r = tt >> 6, d = tt & 63;
        float a = 0.f;
        const float4* wmr = (const float4*)&w_midmini[(size_t)d * 64];
        const float4* sv = (const float4*)&sbuf[r][0];
        #pragma unroll
        for (int e4 = 0; e4 < 16; ++e4) {
            float4 w4 = wmr[e4], s4 = sv[e4];
            a += w4.x * s4.x + w4.y * s4.y + w4.z * s4.z + w4.w * s4.w;
        }
        xc[r][64 + d] = a;
    }
    __syncthreads();

    {
        const int j = t & 127;
        const int g = t >> 7;
        float o0 = 0.f, o1 = 0.f, o2 = 0.f, o3 = 0.f;
        const float4* wfr = (const float4*)&w_final[(size_t)j * 128];
        #pragma unroll 8
        for (int i4 = 0; i4 < 32; ++i4) {
            float4 wf = wfr[i4];
            float4 a0 = *(const float4*)&xc[g + 0][i4 * 4];
            float4 a1 = *(const float4*)&xc[g + 2][i4 * 4];
            float4 a2 = *(const float4*)&xc[g + 4][i4 * 4];
            float4 a3 = *(const float4*)&xc[g + 6][i4 * 4];
            o0 += wf.x * a0.x + wf.y * a0.y + wf.z * a0.z + wf.w * a0.w;
            o1 += wf.x * a1.x + wf.y * a1.y + wf.z * a1.z + wf.w * a1.w;
            o2 += wf.x * a2.x + wf.y * a2.y + wf.z * a2.z + wf.w * a2.w;
            o3 += wf.x * a3.x + wf.y * a3.y + wf.z * a3.z + wf.w * a3.w;
        }
        outpre[(size_t)(n0 + g + 0) * CH + j] = o0;
        outpre[(size_t)(n0 + g + 2) * CH + j] = o1;
        outpre[(size_t)(n0 + g + 4) * CH + j] = o2;
        outpre[(size_t)(n0 + g + 6) * CH + j] = o3;
    }
}

// ---------------- kernel 4: BN partial sums -----------------------------------
__global__ __launch_bounds__(256) void k_bnsum(const float* __restrict__ outpre,
                                               float* __restrict__ bnsum,
                                               float* __restrict__ bnsq)
{
    int j = threadIdx.x & 127, g = threadIdx.x >> 7;
    int b = blockIdx.x;
    float s = 0.f, q = 0.f;
    for (int r = b * 2 + g; r < NQ; r += 128) {
        float v = outpre[(size_t)r * CH + j];
        s += v; q += v * v;
    }
    __shared__ float ls[2][128], lq[2][128];
    ls[g][j] = s; lq[g][j] = q;
    __syncthreads();
    if (g == 0) {
        atomicAdd(&bnsum[j], s + ls[1][j]);
        atomicAdd(&bnsq[j], q + lq[1][j]);
    }
}

// ---------------- kernel 5: BN apply + relu ----------------------------------
__global__ __launch_bounds__(256) void k_bnapply(const float* __restrict__ outpre,
    const float* __restrict__ bnsum, const float* __restrict__ bnsq,
    const float* __restrict__ gamma, const float* __restrict__ beta,
    float* __restrict__ out)
{
    int e4 = blockIdx.x * 256 + threadIdx.x;
    if (e4 >= NQ * CH / 4) return;
    int j0 = (e4 * 4) & 127;
    float4 v = ((const float4*)outpre)[e4];
    float vv[4] = {v.x, v.y, v.z, v.w};
    float res[4];
    #pragma unroll
    for (int i = 0; i < 4; ++i) {
        int j = j0 + i;
        float mean = bnsum[j] * (1.0f / NQ);
        float var = bnsq[j] * (1.0f / NQ) - mean * mean;
        float rstd = rsqrtf(fmaxf(var, 0.f) + EPSN);
        float r = (vv[i] - mean) * rstd * gamma[j] + beta[j];
        res[i] = fmaxf(r, 0.f);
    }
    ((float4*)out)[e4] = make_float4(res[0], res[1], res[2], res[3]);
}

extern "C" void kernel_launch(void* const* d_in, const int* in_sizes, int n_in,
                              void* d_out, int out_size, void* d_ws, size_t ws_size,
                              hipStream_t stream) {
    const float* q_pts     = (const float*)d_in[0];
    const float* s_pts     = (const float*)d_in[1];
    const int*   inds      = (const int*)d_in[2];
    const float* x         = (const float*)d_in[3];
    const int*   stacklen  = (const int*)d_in[4];
    const float* kp_mini   = (const float*)d_in[5];
    const float* w_mini    = (const float*)d_in[6];
    const float* kp_mid    = (const float*)d_in[7];
    const float* w_mid     = (const float*)d_in[8];
    const float* w_midmini = (const float*)d_in[9];
    const float* w_final   = (const float*)d_in[10];
    const float* gamma     = (const float*)d_in[11];
    const float* beta      = (const float*)d_in[12];

    float* ws      = (float*)d_ws;
    float* rowsum  = ws + OFF_ROWSUM;
    float* y1      = ws + OFF_Y1;
    float* y2      = ws + OFF_Y2;
    float* segst   = ws + OFF_SEG;
    float* segsum  = ws + OFF_SEGSUM;
    float* bnsum   = ws + OFF_BNSUM;
    float* bnsq    = ws + OFF_BNSQ;
    float* outpre  = ws + OFF_OUTPRE;
    unsigned short* wswz = (unsigned short*)(ws + OFF_WSWZ);
    unsigned short* P    = (unsigned short*)(ws + OFF_P);

    hipMemsetAsync(segsum, 0, (512 + 256) * sizeof(float), stream);

    k_rowsum<<<MS / 4, 256, 0, stream>>>(x, rowsum);

    if (ws_size >= (size_t)TOT_FLOATS * sizeof(float)) {
        k_wprep<<<(NKT * 8 * 512 + 255) / 256, 256, 0, stream>>>(w_mini, w_mid, wswz);
        k_gather<<<NQ / 4, 256, 0, stream>>>(q_pts, s_pts, inds, x, kp_mini, kp_mid,
                                             rowsum, P);
        k_mfma<<<(NQ / 16 + 3) / 4, 256, 0, stream>>>(P, wswz, y1, y2);
    } else {
        k_kpconv<<<NQ / 4, 256, 0, stream>>>(q_pts, s_pts, inds, x, kp_mini, kp_mid,
                                             w_mini, w_mid, rowsum, y1, y2);
    }

    k_segpart<<<256, 256, 0, stream>>>(y1, y2, stacklen, segsum);
    k_segfin<<<1, 256, 0, stream>>>(segsum, stacklen, segst);
    k_tail<<<NQ / 8, 256, 0, stream>>>(y1, y2, segst, stacklen, w_midmini, w_final, outpre);
    k_bnsum<<<64, 256, 0, stream>>>(outpre, bnsum, bnsq);
    k_bnapply<<<(NQ * CH / 4 + 255) / 256, 256, 0, stream>>>(outpre, bnsum, bnsq,
                                                             gamma, beta, (float*)d_out);
}

// Round 4
// 336.209 us; speedup vs baseline: 3.4407x; 1.1211x over previous
//
#include <hip/hip_runtime.h>
#include <math.h>

#define NQ 20000
#define MS 20000
#define HN 32
#define CH 128
#define DH 64
#define KTOT 20
#define KMINI 7
#define EPSN 1e-5f
#define KDIM 2560            // KTOT*CH
#define NKT 80               // KDIM/32

// workspace layout (in float units)
#define OFF_ROWSUM 0
#define OFF_Y1     20480
#define OFF_Y2     (OFF_Y1 + NQ*DH)
#define OFF_SEG    (OFF_Y2 + NQ*DH)           // 512
#define OFF_SEGSUM (OFF_SEG + 512)            // 512, zeroed
#define OFF_BNSUM  (OFF_SEGSUM + 512)         // 128, zeroed
#define OFF_BNSQ   (OFF_BNSUM + 128)          // 128, zeroed
#define OFF_OUTPRE (OFF_BNSQ + 128)           // NQ*CH
#define OFF_WSWZ   (OFF_OUTPRE + NQ*CH)       // 327680 ushort = 163840 floats
#define OFF_P      (OFF_WSWZ + 163840)        // NQ*KDIM ushort
#define TOT_FLOATS (OFF_P + NQ*KDIM/2)

typedef __attribute__((ext_vector_type(8))) short bf16x8;
typedef __attribute__((ext_vector_type(4))) float f32x4;
typedef __attribute__((ext_vector_type(4))) unsigned short us4;

static __device__ inline unsigned short f2bf(float f) {
    unsigned int u = __float_as_uint(f);
    unsigned int r = (u + 0x7fffu + ((u >> 16) & 1u)) >> 16;
    return (unsigned short)r;
}

// ---------------- kernel 0: per-row sum of x (density sign test) --------------
__global__ __launch_bounds__(256) void k_rowsum(const float* __restrict__ x,
                                                float* __restrict__ rowsum) {
    int row = blockIdx.x * 4 + (threadIdx.x >> 6);
    int lane = threadIdx.x & 63;
    if (row >= MS) return;
    double s = (double)x[row * CH + lane] + (double)x[row * CH + 64 + lane];
    #pragma unroll
    for (int off = 32; off > 0; off >>= 1) s += __shfl_down(s, off, 64);
    if (lane == 0) rowsum[row] = (float)s;
}

// ---------------- kernel G: gather + influence -> P bf16 [n][k*128+c] ---------
// 8 rows/block; thread = (row r = t>>5, channel-quad c4 = t&31)
__global__ __launch_bounds__(256) void k_gather(
    const float* __restrict__ q_pts, const float* __restrict__ s_pts,
    const int* __restrict__ inds, const float* __restrict__ x,
    const float* __restrict__ kp_mini, const float* __restrict__ kp_mid,
    const float* __restrict__ rowsum,
    unsigned short* __restrict__ P)
{
    __shared__ __align__(16) float kpts[KTOT][3];
    __shared__ __align__(16) float nb[256][3];
    __shared__ int   nidx[256];
    __shared__ int   vcnt[8];
    __shared__ float winv[8];
    __shared__ __align__(16) float wts[8][HN][KTOT];   // 20 KB

    const int t = threadIdx.x;
    const int n0 = blockIdx.x * 8;

    if (t < KTOT * 3) {
        int k = t / 3, j = t % 3;
        kpts[k][j] = (k < KMINI) ? kp_mini[k * 3 + j] : kp_mid[(k - KMINI) * 3 + j];
    }
    if (t < 8) vcnt[t] = 0;
    __syncthreads();

    {   // 256 threads = 8 rows x 32 neighbors
        int r = t >> 5, h = t & 31;
        int n = n0 + r;
        int idx = inds[n * HN + h];
        nidx[t] = idx;
        float qx = q_pts[n * 3 + 0], qy = q_pts[n * 3 + 1], qz = q_pts[n * 3 + 2];
        nb[t][0] = s_pts[idx * 3 + 0] - qx;
        nb[t][1] = s_pts[idx * 3 + 1] - qy;
        nb[t][2] = s_pts[idx * 3 + 2] - qz;
        if (rowsum[idx] > 0.0f) atomicAdd(&vcnt[r], 1);
    }
    __syncthreads();
    if (t < 8) winv[t] = 1.0f / (float)max(vcnt[t], 1);
    __syncthreads();

    // influences: 8*32*20 = 5120 values
    for (int tt = t; tt < 8 * HN * KTOT; tt += 256) {
        int r = tt / (HN * KTOT);
        int rem = tt % (HN * KTOT);
        int h = rem / KTOT, k = rem % KTOT;
        float dx = nb[r * HN + h][0] - kpts[k][0];
        float dy = nb[r * HN + h][1] - kpts[k][1];
        float dz = nb[r * HN + h][2] - kpts[k][2];
        float sq = dx * dx + dy * dy + dz * dz;
        float dist = sqrtf(fmaxf(sq, 1e-12f));
        float w = fmaxf(1.0f - dist * (1.0f / 0.6f), 0.0f);
        wts[r][h][k] = w * winv[r];
    }
    __syncthreads();

    // accumulate: thread owns row r, channels c4*4..c4*4+3, all 20 k
    const int r = t >> 5;
    const int c4 = t & 31;
    float acc[KTOT][4];
    #pragma unroll
    for (int k = 0; k < KTOT; ++k) {
        acc[k][0] = 0.f; acc[k][1] = 0.f; acc[k][2] = 0.f; acc[k][3] = 0.f;
    }
    const float* wbase = &wts[r][0][0];
    const int* nid = &nidx[r * HN];
    for (int h = 0; h < HN; ++h) {
        int idx = nid[h];
        float4 xv = *(const float4*)&x[(size_t)idx * CH + c4 * 4];
        const float4* wp = (const float4*)(wbase + h * KTOT);
        float warr[20];
        *(float4*)&warr[0]  = wp[0];
        *(float4*)&warr[4]  = wp[1];
        *(float4*)&warr[8]  = wp[2];
        *(float4*)&warr[12] = wp[3];
        *(float4*)&warr[16] = wp[4];
        #pragma unroll
        for (int k = 0; k < KTOT; ++k) {
            float wv = warr[k];
            acc[k][0] += wv * xv.x; acc[k][1] += wv * xv.y;
            acc[k][2] += wv * xv.z; acc[k][3] += wv * xv.w;
        }
    }
    unsigned short* prow = P + (size_t)(n0 + r) * KDIM + c4 * 4;
    #pragma unroll
    for (int k = 0; k < KTOT; ++k) {
        us4 v;
        v[0] = f2bf(acc[k][0]); v[1] = f2bf(acc[k][1]);
        v[2] = f2bf(acc[k][2]); v[3] = f2bf(acc[k][3]);
        *(us4*)(prow + k * CH) = v;
    }
}

// ---------------- kernel W: swizzle weights into MFMA B-fragment order --------
// wswz[((kt*8+nt)*64 + lane)*8 + j] = W[kt*32 + (lane>>4)*8 + j][nt*16 + (lane&15)]
__global__ __launch_bounds__(256) void k_wprep(
    const float* __restrict__ w_mini, const float* __restrict__ w_mid,
    unsigned short* __restrict__ wswz)
{
    int gid = blockIdx.x * 256 + threadIdx.x;
    if (gid >= NKT * 8 * 512) return;
    int j = gid & 7;
    int l = (gid >> 3) & 63;
    int ntkt = gid >> 9;
    int nt = ntkt & 7;
    int kt = ntkt >> 3;
    int kg = kt * 32 + ((l >> 4) << 3) + j;   // 0..2559
    int d  = nt * 16 + (l & 15);              // 0..127
    int k = kg >> 7, c = kg & 127;
    float v = 0.0f;
    if (k < KMINI && d < DH)        v = w_mini[((size_t)k * CH + c) * DH + d];
    else if (k >= KMINI && d >= DH) v = w_mid[((size_t)(k - KMINI) * CH + c) * DH + (d - DH)];
    wswz[gid] = f2bf(v);
}

// ---------------- kernel M: block-diagonal MFMA GEMM (K-split, LDS-staged) ----
// grid = (313, 6). Block: 64 rows x 4 waves; chunk kt ranges {0,14,28,42,56,68,80}.
__global__ __launch_bounds__(256) void k_mfma(
    const unsigned short* __restrict__ P, const unsigned short* __restrict__ wswz,
    float* __restrict__ y1, float* __restrict__ y2)
{
    __shared__ __align__(16) unsigned short tile[64 * 72];  // pitch 72 (2-way = free)
    const int t = threadIdx.x;
    const int l = t & 63;
    const int w = t >> 6;
    const int mbase = blockIdx.x * 64;
    const int chunk = blockIdx.y;
    const int kb = (chunk < 4) ? chunk * 14 : 56 + (chunk - 4) * 12;
    const int ke = (chunk < 4) ? kb + 14 : kb + 12;
    const int ntb = (chunk < 2) ? 0 : 4;

    f32x4 acc[4];
    #pragma unroll
    for (int i = 0; i < 4; ++i) acc[i] = (f32x4){0.f, 0.f, 0.f, 0.f};

    // staging: thread loads 2x16B -> 64 rows x 64 cols (two kt) per step
    const int srow = t >> 2;
    const int sseg = t & 3;
    int grow = mbase + srow; if (grow >= NQ) grow = NQ - 1;
    const unsigned short* gsrc = P + (size_t)grow * KDIM;
    unsigned short* ldst = tile + srow * 72;

    const int arow_lds = (w * 16 + (l & 15)) * 72 + ((l >> 4) << 3);
    const unsigned short* bsrc = wswz + l * 8;

    for (int kt = kb; kt < ke; kt += 2) {
        __syncthreads();
        *(uint4*)(ldst + sseg * 8)      = *(const uint4*)(gsrc + kt * 32 + sseg * 8);
        *(uint4*)(ldst + 32 + sseg * 8) = *(const uint4*)(gsrc + kt * 32 + 32 + sseg * 8);
        __syncthreads();
        #pragma unroll
        for (int j = 0; j < 2; ++j) {
            bf16x8 a = *(const bf16x8*)(tile + arow_lds + j * 32);
            #pragma unroll
            for (int q = 0; q < 4; ++q) {
                bf16x8 b = *(const bf16x8*)(bsrc + (size_t)((kt + j) * 8 + ntb + q) * 512);
                acc[q] = __builtin_amdgcn_mfma_f32_16x16x32_bf16(a, b, acc[q], 0, 0, 0);
            }
        }
    }

    float* ybase = (chunk < 2) ? y1 : y2;
    const int rb = mbase + w * 16 + ((l >> 4) << 2);
    const int c0 = l & 15;
    #pragma unroll
    for (int q = 0; q < 4; ++q) {
        int col = q * 16 + c0;
        #pragma unroll
        for (int reg = 0; reg < 4; ++reg) {
            int row = rb + reg;
            if (row < NQ) atomicAdd(&ybase[(size_t)row * DH + col], acc[q][reg]);
        }
    }
}

// ---------------- FALLBACK: R1 fused kpconv (if ws too small) -----------------
__global__ __launch_bounds__(256) void k_kpconv(
    const float* __restrict__ q_pts, const float* __restrict__ s_pts,
    const int* __restrict__ inds, const float* __restrict__ x,
    const float* __restrict__ kp_mini, const float* __restrict__ kp_mid,
    const float* __restrict__ w_mini, const float* __restrict__ w_mid,
    const float* __restrict__ rowsum,
    float* __restrict__ y1, float* __restrict__ y2)
{
    __shared__ __align__(16) float kpts[KTOT][3];
    __shared__ __align__(16) float nb[128][3];
    __shared__ int   nidx[128];
    __shared__ int   vcnt[4];
    __shared__ float winv[4];
    __shared__ __align__(16) float wts[4][HN][KTOT];
    __shared__ __align__(16) float wt[KTOT][CH][4];
    __shared__ __align__(16) float part[128][4];

    const int t = threadIdx.x;
    const int n0 = blockIdx.x * 4;

    if (t < KTOT * 3) {
        int k = t / 3, j = t % 3;
        kpts[k][j] = (k < KMINI) ? kp_mini[k * 3 + j] : kp_mid[(k - KMINI) * 3 + j];
    }
    if (t < 4) vcnt[t] = 0;
    __syncthreads();

    if (t < 128) {
        int r = t >> 5, h = t & 31;
        int n = n0 + r;
        int idx = inds[n * HN + h];
        nidx[t] = idx;
        float qx = q_pts[n * 3 + 0], qy = q_pts[n * 3 + 1], qz = q_pts[n * 3 + 2];
        nb[t][0] = s_pts[idx * 3 + 0] - qx;
        nb[t][1] = s_pts[idx * 3 + 1] - qy;
        nb[t][2] = s_pts[idx * 3 + 2] - qz;
        if (rowsum[idx] > 0.0f) atomicAdd(&vcnt[r], 1);
    }
    __syncthreads();
    if (t < 4) winv[t] = 1.0f / (float)max(vcnt[t], 1);
    __syncthreads();

    for (int tt = t; tt < 4 * HN * KTOT; tt += 256) {
        int r = tt / (HN * KTOT);
        int rem = tt % (HN * KTOT);
        int h = rem / KTOT, k = rem % KTOT;
        float dx = nb[r * HN + h][0] - kpts[k][0];
        float dy = nb[r * HN + h][1] - kpts[k][1];
        float dz = nb[r * HN + h][2] - kpts[k][2];
        float sq = dx * dx + dy * dy + dz * dz;
        float dist = sqrtf(fmaxf(sq, 1e-12f));
        float w = fmaxf(1.0f - dist * (1.0f / 0.6f), 0.0f);
        wts[r][h][k] = w * winv[r];
    }
    __syncthreads();

    {
        const int g = t >> 7;
        const int c = t & 127;
        for (int rr = 0; rr < 2; ++rr) {
            const int r = g + rr * 2;
            float acc[KTOT];
            #pragma unroll
            for (int k = 0; k < KTOT; ++k) acc[k] = 0.0f;
            for (int h = 0; h < HN; ++h) {
                int idx = nidx[r * HN + h];
                float xv = x[(size_t)idx * CH + c];
                const float4* wp = (const float4*)&wts[r][h][0];
                float4 wa = wp[0], wb = wp[1], wc = wp[2], wd = wp[3], we = wp[4];
                acc[0]  += wa.x * xv; acc[1]  += wa.y * xv; acc[2]  += wa.z * xv; acc[3]  += wa.w * xv;
                acc[4]  += wb.x * xv; acc[5]  += wb.y * xv; acc[6]  += wb.z * xv; acc[7]  += wb.w * xv;
                acc[8]  += wc.x * xv; acc[9]  += wc.y * xv; acc[10] += wc.z * xv; acc[11] += wc.w * xv;
                acc[12] += wd.x * xv; acc[13] += wd.y * xv; acc[14] += wd.z * xv; acc[15] += wd.w * xv;
                acc[16] += we.x * xv; acc[17] += we.y * xv; acc[18] += we.z * xv; acc[19] += we.w * xv;
            }
            #pragma unroll
            for (int k = 0; k < KTOT; ++k) wt[k][c][r] = acc[k];
        }
    }
    __syncthreads();

    {
        const int d = t & 127;
        const int half = t >> 7;
        const int c0 = half * 64;
        float o0 = 0.f, o1 = 0.f, o2 = 0.f, o3 = 0.f;
        if (d < DH) {
            for (int k = 0; k < KMINI; ++k) {
                const float* wp = &w_mini[((size_t)k * CH + c0) * DH + d];
                for (int c = c0; c < c0 + 64; ++c) {
                    float wv = *wp; wp += DH;
                    const float4 wtv = *(const float4*)&wt[k][c][0];
                    o0 += wv * wtv.x; o1 += wv * wtv.y; o2 += wv * wtv.z; o3 += wv * wtv.w;
                }
            }
        } else {
            const int dd = d - DH;
            for (int k = KMINI; k < KTOT; ++k) {
                const float* wp = &w_mid[((size_t)(k - KMINI) * CH + c0) * DH + dd];
                for (int c = c0; c < c0 + 64; ++c) {
                    float wv = *wp; wp += DH;
                    const float4 wtv = *(const float4*)&wt[k][c][0];
                    o0 += wv * wtv.x; o1 += wv * wtv.y; o2 += wv * wtv.z; o3 += wv * wtv.w;
                }
            }
        }
        if (half == 1) { part[d][0] = o0; part[d][1] = o1; part[d][2] = o2; part[d][3] = o3; }
        __syncthreads();
        if (half == 0) {
            o0 += part[d][0]; o1 += part[d][1]; o2 += part[d][2]; o3 += part[d][3];
            if (d < DH) {
                y1[(size_t)(n0 + 0) * DH + d] = o0;
                y1[(size_t)(n0 + 1) * DH + d] = o1;
                y1[(size_t)(n0 + 2) * DH + d] = o2;
                y1[(size_t)(n0 + 3) * DH + d] = o3;
            } else {
                const int dd = d - DH;
                y2[(size_t)(n0 + 0) * DH + dd] = o0;
                y2[(size_t)(n0 + 1) * DH + dd] = o1;
                y2[(size_t)(n0 + 2) * DH + dd] = o2;
                y2[(size_t)(n0 + 3) * DH + dd] = o3;
            }
        }
    }
}

// -------- kernel 2a: parallel per-segment partial sums ------------------------
__global__ __launch_bounds__(256) void k_segpart(
    const float* __restrict__ y1, const float* __restrict__ y2,
    const int* __restrict__ stacklen, float* __restrict__ segsum)
{
    const int t = threadIdx.x;
    const int ch = t & 63, grp = t >> 6;
    const int len0 = stacklen[0];
    float a0 = 0.f, a1 = 0.f, a2 = 0.f, a3 = 0.f;
    float b0 = 0.f, b1 = 0.f, b2 = 0.f, b3 = 0.f;
    for (int r = blockIdx.x * 4 + grp; r < NQ; r += 256 * 4) {
        float v1 = y1[(size_t)r * DH + ch];
        float v2 = y2[(size_t)r * DH + ch];
        bool in1 = (r >= len0);
        float m0 = in1 ? 0.f : 1.f, m1 = 1.f - m0;
        a0 += m0 * v1; a1 += m0 * v1 * v1; a2 += m1 * v1; a3 += m1 * v1 * v1;
        b0 += m0 * v2; b1 += m0 * v2 * v2; b2 += m1 * v2; b3 += m1 * v2 * v2;
    }
    __shared__ float red[4][8][64];
    red[grp][0][ch] = a0; red[grp][1][ch] = a1; red[grp][2][ch] = a2; red[grp][3][ch] = a3;
    red[grp][4][ch] = b0; red[grp][5][ch] = b1; red[grp][6][ch] = b2; red[grp][7][ch] = b3;
    __syncthreads();
    for (int tt = t; tt < 512; tt += 256) {
        int j = tt >> 6, c = tt & 63;
        float s = red[0][j][c] + red[1][j][c] + red[2][j][c] + red[3][j][c];
        atomicAdd(&segsum[j * 64 + c], s);
    }
}

// -------- kernel 2b: finalize mean/rstd ---------------------------------------
__global__ __launch_bounds__(256) void k_segfin(
    const float* __restrict__ segsum, const int* __restrict__ stacklen,
    float* __restrict__ segstats)
{
    const int t = threadIdx.x;
    const int combo = t >> 6;
    const int ch = t & 63;
    const int len0 = stacklen[0];
    const int s = combo & 1;
    float cnt = (float)max(s ? (NQ - len0) : len0, 1);
    float S = segsum[(combo * 2 + 0) * 64 + ch];
    float Q = segsum[(combo * 2 + 1) * 64 + ch];
    float mean = S / cnt;
    float var = Q / cnt - mean * mean;
    float rstd = rsqrtf(fmaxf(var, 0.f) + EPSN);
    segstats[combo * 128 + ch] = mean;
    segstats[combo * 128 + 64 + ch] = rstd;
}

// ------- kernel 3: segment-norm + midmini linear + concat + final linear ------
__global__ __launch_bounds__(256) void k_tail(
    const float* __restrict__ y1, const float* __restrict__ y2,
    const float* __restrict__ segstats, const int* __restrict__ stacklen,
    const float* __restrict__ w_midmini, const float* __restrict__ w_final,
    float* __restrict__ outpre)
{
    __shared__ __align__(16) float sbuf[8][64];
    __shared__ __align__(16) float xc[8][128];
    const int n0 = blockIdx.x * 8;
    const int t = threadIdx.x;
    const int len0 = stacklen[0];

    for (int tt = t; tt < 8 * 64; tt += 256) {
        int r = tt >> 6, d = tt & 63;
        int n = n0 + r;
        int s = (n >= len0) ? 1 : 0;
        float m1 = segstats[s * 128 + d],        r1 = segstats[s * 128 + 64 + d];
        float m2 = segstats[(2 + s) * 128 + d],  r2 = segstats[(2 + s) * 128 + 64 + d];
        float x1n = (y1[(size_t)n * DH + d] - m1) * r1;
        float x2n = (y2[(size_t)n * DH + d] - m2) * r2;
        xc[r][d] = x1n;
        sbuf[r][d] = x1n + x2n;
    }
    __syncthreads();

    for (int tt = t; tt < 8 * 64; tt += 256) {
        int r = tt >> 6, d = tt & 63;
        float a = 0.f;
        const float4* wmr = (const float4*)&w_midmini[(size_t)d * 64];
        const float4* sv = (const float4*)&sbuf[r][0];
        #pragma unroll
        for (int e4 = 0; e4 < 16; ++e4) {
            float4 w4 = wmr[e4], s4 = sv[e4];
            a += w4.x * s4.x + w4.y * s4.y + w4.z * s4.z + w4.w * s4.w;
        }
        xc[r][64 + d] = a;
    }
    __syncthreads();

    {
        const int j = t & 127;
        const int g = t >> 7;
        float o0 = 0.f, o1 = 0.f, o2 = 0.f, o3 = 0.f;
        const float4* wfr = (const float4*)&w_final[(size_t)j * 128];
        #pragma unroll 8
        for (int i4 = 0; i4 < 32; ++i4) {
            float4 wf = wfr[i4];
            float4 a0 = *(const float4*)&xc[g + 0][i4 * 4];
            float4 a1 = *(const float4*)&xc[g + 2][i4 * 4];
            float4 a2 = *(const float4*)&xc[g + 4][i4 * 4];
            float4 a3 = *(const float4*)&xc[g + 6][i4 * 4];
            o0 += wf.x * a0.x + wf.y * a0.y + wf.z * a0.z + wf.w * a0.w;
            o1 += wf.x * a1.x + wf.y * a1.y + wf.z * a1.z + wf.w * a1.w;
            o2 += wf.x * a2.x + wf.y * a2.y + wf.z * a2.z + wf.w * a2.w;
            o3 += wf.x * a3.x + wf.y * a3.y + wf.z * a3.z + wf.w * a3.w;
        }
        outpre[(size_t)(n0 + g + 0) * CH + j] = o0;
        outpre[(size_t)(n0 + g + 2) * CH + j] = o1;
        outpre[(size_t)(n0 + g + 4) * CH + j] = o2;
        outpre[(size_t)(n0 + g + 6) * CH + j] = o3;
    }
}

// ---------------- kernel 4: BN partial sums -----------------------------------
__global__ __launch_bounds__(256) void k_bnsum(const float* __restrict__ outpre,
                                               float* __restrict__ bnsum,
                                               float* __restrict__ bnsq)
{
    int j = threadIdx.x & 127, g = threadIdx.x >> 7;
    int b = blockIdx.x;
    float s = 0.f, q = 0.f;
    for (int r = b * 2 + g; r < NQ; r += 128) {
        float v = outpre[(size_t)r * CH + j];
        s += v; q += v * v;
    }
    __shared__ float ls[2][128], lq[2][128];
    ls[g][j] = s; lq[g][j] = q;
    __syncthreads();
    if (g == 0) {
        atomicAdd(&bnsum[j], s + ls[1][j]);
        atomicAdd(&bnsq[j], q + lq[1][j]);
    }
}

// ---------------- kernel 5: BN apply + relu ----------------------------------
__global__ __launch_bounds__(256) void k_bnapply(const float* __restrict__ outpre,
    const float* __restrict__ bnsum, const float* __restrict__ bnsq,
    const float* __restrict__ gamma, const float* __restrict__ beta,
    float* __restrict__ out)
{
    int e4 = blockIdx.x * 256 + threadIdx.x;
    if (e4 >= NQ * CH / 4) return;
    int j0 = (e4 * 4) & 127;
    float4 v = ((const float4*)outpre)[e4];
    float vv[4] = {v.x, v.y, v.z, v.w};
    float res[4];
    #pragma unroll
    for (int i = 0; i < 4; ++i) {
        int j = j0 + i;
        float mean = bnsum[j] * (1.0f / NQ);
        float var = bnsq[j] * (1.0f / NQ) - mean * mean;
        float rstd = rsqrtf(fmaxf(var, 0.f) + EPSN);
        float r = (vv[i] - mean) * rstd * gamma[j] + beta[j];
        res[i] = fmaxf(r, 0.f);
    }
    ((float4*)out)[e4] = make_float4(res[0], res[1], res[2], res[3]);
}

extern "C" void kernel_launch(void* const* d_in, const int* in_sizes, int n_in,
                              void* d_out, int out_size, void* d_ws, size_t ws_size,
                              hipStream_t stream) {
    const float* q_pts     = (const float*)d_in[0];
    const float* s_pts     = (const float*)d_in[1];
    const int*   inds      = (const int*)d_in[2];
    const float* x         = (const float*)d_in[3];
    const int*   stacklen  = (const int*)d_in[4];
    const float* kp_mini   = (const float*)d_in[5];
    const float* w_mini    = (const float*)d_in[6];
    const float* kp_mid    = (const float*)d_in[7];
    const float* w_mid     = (const float*)d_in[8];
    const float* w_midmini = (const float*)d_in[9];
    const float* w_final   = (const float*)d_in[10];
    const float* gamma     = (const float*)d_in[11];
    const float* beta      = (const float*)d_in[12];

    float* ws      = (float*)d_ws;
    float* rowsum  = ws + OFF_ROWSUM;
    float* y1      = ws + OFF_Y1;
    float* y2      = ws + OFF_Y2;
    float* segst   = ws + OFF_SEG;
    float* segsum  = ws + OFF_SEGSUM;
    float* bnsum   = ws + OFF_BNSUM;
    float* bnsq    = ws + OFF_BNSQ;
    float* outpre  = ws + OFF_OUTPRE;
    unsigned short* wswz = (unsigned short*)(ws + OFF_WSWZ);
    unsigned short* P    = (unsigned short*)(ws + OFF_P);

    hipMemsetAsync(segsum, 0, (512 + 256) * sizeof(float), stream);

    k_rowsum<<<MS / 4, 256, 0, stream>>>(x, rowsum);

    if (ws_size >= (size_t)TOT_FLOATS * sizeof(float)) {
        hipMemsetAsync(y1, 0, (size_t)NQ * DH * 2 * sizeof(float), stream);
        k_wprep<<<(NKT * 8 * 512 + 255) / 256, 256, 0, stream>>>(w_mini, w_mid, wswz);
        k_gather<<<NQ / 8, 256, 0, stream>>>(q_pts, s_pts, inds, x, kp_mini, kp_mid,
                                             rowsum, P);
        dim3 mg((NQ / 16 + 3) / 4, 6);
        k_mfma<<<mg, 256, 0, stream>>>(P, wswz, y1, y2);
    } else {
        k_kpconv<<<NQ / 4, 256, 0, stream>>>(q_pts, s_pts, inds, x, kp_mini, kp_mid,
                                             w_mini, w_mid, rowsum, y1, y2);
    }

    k_segpart<<<256, 256, 0, stream>>>(y1, y2, stacklen, segsum);
    k_segfin<<<1, 256, 0, stream>>>(segsum, stacklen, segst);
    k_tail<<<NQ / 8, 256, 0, stream>>>(y1, y2, segst, stacklen, w_midmini, w_final, outpre);
    k_bnsum<<<64, 256, 0, stream>>>(outpre, bnsum, bnsq);
    k_bnapply<<<(NQ * CH / 4 + 255) / 256, 256, 0, stream>>>(outpre, bnsum, bnsq,
                                                             gamma, beta, (float*)d_out);
}

// Round 5
// 295.906 us; speedup vs baseline: 3.9093x; 1.1362x over previous
//
#include <hip/hip_runtime.h>
#include <math.h>

#define NQ 20000
#define MS 20000
#define HN 32
#define CH 128
#define DH 64
#define KTOT 20
#define KMINI 7
#define EPSN 1e-5f
#define KDIM 2560            // KTOT*CH
#define NKT 80               // KDIM/32
#define NMT 1250             // NQ/16
#define KT_Y1 28             // kt < 28 -> y1 (k<7), else y2

// workspace layout (in float units)
#define OFF_ROWSUM 0
#define OFF_Y1     20480
#define OFF_Y2     (OFF_Y1 + NQ*DH)
#define OFF_SEG    (OFF_Y2 + NQ*DH)           // 512 (unused, kept for layout)
#define OFF_SEGSUM (OFF_SEG + 512)            // 512, zeroed
#define OFF_BNSUM  (OFF_SEGSUM + 512)         // 128, zeroed
#define OFF_BNSQ   (OFF_BNSUM + 128)          // 128, zeroed
#define OFF_OUTPRE (OFF_BNSQ + 128)           // NQ*CH
#define OFF_WSWZ   (OFF_OUTPRE + NQ*CH)       // 327680 ushort = 163840 floats
#define OFF_P      (OFF_WSWZ + 163840)        // NQ*KDIM ushort (frag-ordered)
#define TOT_FLOATS (OFF_P + NQ*KDIM/2)

typedef __attribute__((ext_vector_type(8))) short bf16x8;
typedef __attribute__((ext_vector_type(4))) float f32x4;
typedef __attribute__((ext_vector_type(4))) unsigned short us4;

static __device__ inline unsigned short f2bf(float f) {
    unsigned int u = __float_as_uint(f);
    unsigned int r = (u + 0x7fffu + ((u >> 16) & 1u)) >> 16;
    return (unsigned short)r;
}

// ------------- kernel P: rowsum (blocks <5000) + weight swizzle (rest) --------
__global__ __launch_bounds__(256) void k_prep(
    const float* __restrict__ x, float* __restrict__ rowsum,
    const float* __restrict__ w_mini, const float* __restrict__ w_mid,
    unsigned short* __restrict__ wswz)
{
    if (blockIdx.x < 5000) {
        int row = blockIdx.x * 4 + (threadIdx.x >> 6);
        int lane = threadIdx.x & 63;
        if (row >= MS) return;
        double s = (double)x[row * CH + lane] + (double)x[row * CH + 64 + lane];
        #pragma unroll
        for (int off = 32; off > 0; off >>= 1) s += __shfl_down(s, off, 64);
        if (lane == 0) rowsum[row] = (float)s;
    } else {
        int gid = (blockIdx.x - 5000) * 256 + threadIdx.x;
        if (gid >= NKT * 8 * 512) return;
        int j = gid & 7;
        int l = (gid >> 3) & 63;
        int ntkt = gid >> 9;
        int nt = ntkt & 7;
        int kt = ntkt >> 3;
        int kg = kt * 32 + ((l >> 4) << 3) + j;
        int d  = nt * 16 + (l & 15);
        int k = kg >> 7, c = kg & 127;
        float v = 0.0f;
        if (k < KMINI && d < DH)        v = w_mini[((size_t)k * CH + c) * DH + d];
        else if (k >= KMINI && d >= DH) v = w_mid[((size_t)(k - KMINI) * CH + c) * DH + (d - DH)];
        wswz[gid] = f2bf(v);
    }
}

// ---------------- kernel G: gather + influence -> Pfrag (MFMA A-frag order) ---
// Pfrag[(mt*80+kt)*512 + l*8 + j] = P[mt*16 + (l&15)][kt*32 + (l>>4)*8 + j]
__global__ __launch_bounds__(256) void k_gather(
    const float* __restrict__ q_pts, const float* __restrict__ s_pts,
    const int* __restrict__ inds, const float* __restrict__ x,
    const float* __restrict__ kp_mini, const float* __restrict__ kp_mid,
    const float* __restrict__ rowsum,
    unsigned short* __restrict__ P)
{
    __shared__ __align__(16) float kpts[KTOT][3];
    __shared__ __align__(16) float nb[256][3];
    __shared__ int   nidx[256];
    __shared__ int   vcnt[8];
    __shared__ float winv[8];
    __shared__ __align__(16) float wts[8][HN][KTOT];

    const int t = threadIdx.x;
    const int n0 = blockIdx.x * 8;

    if (t < KTOT * 3) {
        int k = t / 3, j = t % 3;
        kpts[k][j] = (k < KMINI) ? kp_mini[k * 3 + j] : kp_mid[(k - KMINI) * 3 + j];
    }
    if (t < 8) vcnt[t] = 0;
    __syncthreads();

    {   // 256 threads = 8 rows x 32 neighbors
        int r = t >> 5, h = t & 31;
        int n = n0 + r;
        int idx = inds[n * HN + h];
        nidx[t] = idx;
        float qx = q_pts[n * 3 + 0], qy = q_pts[n * 3 + 1], qz = q_pts[n * 3 + 2];
        nb[t][0] = s_pts[idx * 3 + 0] - qx;
        nb[t][1] = s_pts[idx * 3 + 1] - qy;
        nb[t][2] = s_pts[idx * 3 + 2] - qz;
        if (rowsum[idx] > 0.0f) atomicAdd(&vcnt[r], 1);
    }
    __syncthreads();
    if (t < 8) winv[t] = 1.0f / (float)max(vcnt[t], 1);
    __syncthreads();

    for (int tt = t; tt < 8 * HN * KTOT; tt += 256) {
        int r = tt / (HN * KTOT);
        int rem = tt % (HN * KTOT);
        int h = rem / KTOT, k = rem % KTOT;
        float dx = nb[r * HN + h][0] - kpts[k][0];
        float dy = nb[r * HN + h][1] - kpts[k][1];
        float dz = nb[r * HN + h][2] - kpts[k][2];
        float sq = dx * dx + dy * dy + dz * dz;
        float dist = sqrtf(fmaxf(sq, 1e-12f));
        float w = fmaxf(1.0f - dist * (1.0f / 0.6f), 0.0f);
        wts[r][h][k] = w * winv[r];
    }
    __syncthreads();

    const int r = t >> 5;
    const int c4 = t & 31;
    float acc[KTOT][4];
    #pragma unroll
    for (int k = 0; k < KTOT; ++k) {
        acc[k][0] = 0.f; acc[k][1] = 0.f; acc[k][2] = 0.f; acc[k][3] = 0.f;
    }
    const float* wbase = &wts[r][0][0];
    const int* nid = &nidx[r * HN];
    #pragma unroll 2
    for (int h = 0; h < HN; ++h) {
        int idx = nid[h];
        float4 xv = *(const float4*)&x[(size_t)idx * CH + c4 * 4];
        const float4* wp = (const float4*)(wbase + h * KTOT);
        float warr[20];
        *(float4*)&warr[0]  = wp[0];
        *(float4*)&warr[4]  = wp[1];
        *(float4*)&warr[8]  = wp[2];
        *(float4*)&warr[12] = wp[3];
        *(float4*)&warr[16] = wp[4];
        #pragma unroll
        for (int k = 0; k < KTOT; ++k) {
            float wv = warr[k];
            acc[k][0] += wv * xv.x; acc[k][1] += wv * xv.y;
            acc[k][2] += wv * xv.z; acc[k][3] += wv * xv.w;
        }
    }
    // frag-ordered store
    const int n = n0 + r;
    const int mt = n >> 4, m15 = n & 15;
    const int lq = (c4 & 7) >> 1;            // quad within lane group
    const int l = lq * 16 + m15;             // MFMA lane
    const int j = (c4 & 1) * 4;              // element offset within lane's 8
    #pragma unroll
    for (int k = 0; k < KTOT; ++k) {
        int kt = k * 4 + (c4 >> 3);
        us4 v;
        v[0] = f2bf(acc[k][0]); v[1] = f2bf(acc[k][1]);
        v[2] = f2bf(acc[k][2]); v[3] = f2bf(acc[k][3]);
        *(us4*)(P + ((size_t)mt * NKT + kt) * 512 + l * 8 + j) = v;
    }
}

// ---------------- kernel M: frag-direct MFMA GEMM + fused segment stats -------
// grid (157, 2): blockIdx.y = chunk (0: kt 0..27 -> y1, 1: kt 28..79 -> y2)
// block = 4 waves, each wave handles 2 M-tiles.
__global__ __launch_bounds__(256) void k_mfma(
    const unsigned short* __restrict__ P, const unsigned short* __restrict__ wswz,
    const int* __restrict__ stacklen,
    float* __restrict__ y1, float* __restrict__ y2, float* __restrict__ segsum)
{
    const int t = threadIdx.x;
    const int l = t & 63;
    const int w = t >> 6;
    const int chunk = blockIdx.y;
    const int mtb = blockIdx.x * 8 + w * 2;
    if (mtb >= NMT) return;
    const int kb = chunk ? KT_Y1 : 0;
    const int ke = chunk ? NKT : KT_Y1;
    const int ntb = chunk ? 4 : 0;

    f32x4 acc[2][4];
    #pragma unroll
    for (int i = 0; i < 2; ++i)
        #pragma unroll
        for (int q = 0; q < 4; ++q) acc[i][q] = (f32x4){0.f, 0.f, 0.f, 0.f};

    const size_t astride = (size_t)NKT * 512;
    const unsigned short* a0p = P + (size_t)mtb * astride + l * 8;
    const unsigned short* a1p = (mtb + 1 < NMT) ? a0p + astride : a0p;
    const unsigned short* bp = wswz + l * 8;

    #pragma unroll 2
    for (int kt = kb; kt < ke; ++kt) {
        bf16x8 a0 = *(const bf16x8*)(a0p + (size_t)kt * 512);
        bf16x8 a1 = *(const bf16x8*)(a1p + (size_t)kt * 512);
        #pragma unroll
        for (int q = 0; q < 4; ++q) {
            bf16x8 b = *(const bf16x8*)(bp + (size_t)((kt * 8) + ntb + q) * 512);
            acc[0][q] = __builtin_amdgcn_mfma_f32_16x16x32_bf16(a0, b, acc[0][q], 0, 0, 0);
            acc[1][q] = __builtin_amdgcn_mfma_f32_16x16x32_bf16(a1, b, acc[1][q], 0, 0, 0);
        }
    }

    const int len0 = stacklen[0];
    float* yb = chunk ? y2 : y1;
    const int quad = l >> 4, c16 = l & 15;
    const int base_sum = (chunk * 2) * 2 * 64;   // combo = chunk*2 + seg; slot (combo*2+isq)*64

    #pragma unroll
    for (int i = 0; i < 2; ++i) {
        int mt = mtb + i;
        if (mt >= NMT) break;
        bool all0 = (mt * 16 + 15 < len0);
        bool all1 = (mt * 16 >= len0);
        #pragma unroll
        for (int q = 0; q < 4; ++q) {
            float s0 = 0.f, q0 = 0.f, s1 = 0.f, q1 = 0.f;
            #pragma unroll
            for (int reg = 0; reg < 4; ++reg) {
                int row = mt * 16 + quad * 4 + reg;
                float v = acc[i][q][reg];
                yb[(size_t)row * DH + q * 16 + c16] = v;
                if (row < len0) { s0 += v; q0 += v * v; }
                else            { s1 += v; q1 += v * v; }
            }
            // reduce across quads (rows) -> lanes 0..15 hold per-channel sums
            s0 += __shfl_xor(s0, 16); s0 += __shfl_xor(s0, 32);
            q0 += __shfl_xor(q0, 16); q0 += __shfl_xor(q0, 32);
            s1 += __shfl_xor(s1, 16); s1 += __shfl_xor(s1, 32);
            q1 += __shfl_xor(q1, 16); q1 += __shfl_xor(q1, 32);
            if (quad == 0) {
                int ch = q * 16 + c16;
                if (!all1) {
                    atomicAdd(&segsum[base_sum + 0 * 64 + ch], s0);
                    atomicAdd(&segsum[base_sum + 1 * 64 + ch], q0);
                }
                if (!all0) {
                    atomicAdd(&segsum[base_sum + 2 * 64 + ch], s1);
                    atomicAdd(&segsum[base_sum + 3 * 64 + ch], q1);
                }
            }
        }
    }
}

// ---------------- FALLBACK: R1 fused kpconv (if ws too small) -----------------
__global__ __launch_bounds__(256) void k_kpconv(
    const float* __restrict__ q_pts, const float* __restrict__ s_pts,
    const int* __restrict__ inds, const float* __restrict__ x,
    const float* __restrict__ kp_mini, const float* __restrict__ kp_mid,
    const float* __restrict__ w_mini, const float* __restrict__ w_mid,
    const float* __restrict__ rowsum,
    float* __restrict__ y1, float* __restrict__ y2)
{
    __shared__ __align__(16) float kpts[KTOT][3];
    __shared__ __align__(16) float nb[128][3];
    __shared__ int   nidx[128];
    __shared__ int   vcnt[4];
    __shared__ float winv[4];
    __shared__ __align__(16) float wts[4][HN][KTOT];
    __shared__ __align__(16) float wt[KTOT][CH][4];
    __shared__ __align__(16) float part[128][4];

    const int t = threadIdx.x;
    const int n0 = blockIdx.x * 4;

    if (t < KTOT * 3) {
        int k = t / 3, j = t % 3;
        kpts[k][j] = (k < KMINI) ? kp_mini[k * 3 + j] : kp_mid[(k - KMINI) * 3 + j];
    }
    if (t < 4) vcnt[t] = 0;
    __syncthreads();

    if (t < 128) {
        int r = t >> 5, h = t & 31;
        int n = n0 + r;
        int idx = inds[n * HN + h];
        nidx[t] = idx;
        float qx = q_pts[n * 3 + 0], qy = q_pts[n * 3 + 1], qz = q_pts[n * 3 + 2];
        nb[t][0] = s_pts[idx * 3 + 0] - qx;
        nb[t][1] = s_pts[idx * 3 + 1] - qy;
        nb[t][2] = s_pts[idx * 3 + 2] - qz;
        if (rowsum[idx] > 0.0f) atomicAdd(&vcnt[r], 1);
    }
    __syncthreads();
    if (t < 4) winv[t] = 1.0f / (float)max(vcnt[t], 1);
    __syncthreads();

    for (int tt = t; tt < 4 * HN * KTOT; tt += 256) {
        int r = tt / (HN * KTOT);
        int rem = tt % (HN * KTOT);
        int h = rem / KTOT, k = rem % KTOT;
        float dx = nb[r * HN + h][0] - kpts[k][0];
        float dy = nb[r * HN + h][1] - kpts[k][1];
        float dz = nb[r * HN + h][2] - kpts[k][2];
        float sq = dx * dx + dy * dy + dz * dz;
        float dist = sqrtf(fmaxf(sq, 1e-12f));
        float w = fmaxf(1.0f - dist * (1.0f / 0.6f), 0.0f);
        wts[r][h][k] = w * winv[r];
    }
    __syncthreads();

    {
        const int g = t >> 7;
        const int c = t & 127;
        for (int rr = 0; rr < 2; ++rr) {
            const int r = g + rr * 2;
            float acc[KTOT];
            #pragma unroll
            for (int k = 0; k < KTOT; ++k) acc[k] = 0.0f;
            for (int h = 0; h < HN; ++h) {
                int idx = nidx[r * HN + h];
                float xv = x[(size_t)idx * CH + c];
                const float4* wp = (const float4*)&wts[r][h][0];
                float4 wa = wp[0], wb = wp[1], wc = wp[2], wd = wp[3], we = wp[4];
                acc[0]  += wa.x * xv; acc[1]  += wa.y * xv; acc[2]  += wa.z * xv; acc[3]  += wa.w * xv;
                acc[4]  += wb.x * xv; acc[5]  += wb.y * xv; acc[6]  += wb.z * xv; acc[7]  += wb.w * xv;
                acc[8]  += wc.x * xv; acc[9]  += wc.y * xv; acc[10] += wc.z * xv; acc[11] += wc.w * xv;
                acc[12] += wd.x * xv; acc[13] += wd.y * xv; acc[14] += wd.z * xv; acc[15] += wd.w * xv;
                acc[16] += we.x * xv; acc[17] += we.y * xv; acc[18] += we.z * xv; acc[19] += we.w * xv;
            }
            #pragma unroll
            for (int k = 0; k < KTOT; ++k) wt[k][c][r] = acc[k];
        }
    }
    __syncthreads();

    {
        const int d = t & 127;
        const int half = t >> 7;
        const int c0 = half * 64;
        float o0 = 0.f, o1 = 0.f, o2 = 0.f, o3 = 0.f;
        if (d < DH) {
            for (int k = 0; k < KMINI; ++k) {
                const float* wp = &w_mini[((size_t)k * CH + c0) * DH + d];
                for (int c = c0; c < c0 + 64; ++c) {
                    float wv = *wp; wp += DH;
                    const float4 wtv = *(const float4*)&wt[k][c][0];
                    o0 += wv * wtv.x; o1 += wv * wtv.y; o2 += wv * wtv.z; o3 += wv * wtv.w;
                }
            }
        } else {
            const int dd = d - DH;
            for (int k = KMINI; k < KTOT; ++k) {
                const float* wp = &w_mid[((size_t)(k - KMINI) * CH + c0) * DH + dd];
                for (int c = c0; c < c0 + 64; ++c) {
                    float wv = *wp; wp += DH;
                    const float4 wtv = *(const float4*)&wt[k][c][0];
                    o0 += wv * wtv.x; o1 += wv * wtv.y; o2 += wv * wtv.z; o3 += wv * wtv.w;
                }
            }
        }
        if (half == 1) { part[d][0] = o0; part[d][1] = o1; part[d][2] = o2; part[d][3] = o3; }
        __syncthreads();
        if (half == 0) {
            o0 += part[d][0]; o1 += part[d][1]; o2 += part[d][2]; o3 += part[d][3];
            if (d < DH) {
                y1[(size_t)(n0 + 0) * DH + d] = o0;
                y1[(size_t)(n0 + 1) * DH + d] = o1;
                y1[(size_t)(n0 + 2) * DH + d] = o2;
                y1[(size_t)(n0 + 3) * DH + d] = o3;
            } else {
                const int dd = d - DH;
                y2[(size_t)(n0 + 0) * DH + dd] = o0;
                y2[(size_t)(n0 + 1) * DH + dd] = o1;
                y2[(size_t)(n0 + 2) * DH + dd] = o2;
                y2[(size_t)(n0 + 3) * DH + dd] = o3;
            }
        }
    }
}

// -------- fallback-only: parallel per-segment partial sums --------------------
__global__ __launch_bounds__(256) void k_segpart(
    const float* __restrict__ y1, const float* __restrict__ y2,
    const int* __restrict__ stacklen, float* __restrict__ segsum)
{
    const int t = threadIdx.x;
    const int ch = t & 63, grp = t >> 6;
    const int len0 = stacklen[0];
    float a0 = 0.f, a1 = 0.f, a2 = 0.f, a3 = 0.f;
    float b0 = 0.f, b1 = 0.f, b2 = 0.f, b3 = 0.f;
    for (int r = blockIdx.x * 4 + grp; r < NQ; r += 256 * 4) {
        float v1 = y1[(size_t)r * DH + ch];
        float v2 = y2[(size_t)r * DH + ch];
        bool in1 = (r >= len0);
        float m0 = in1 ? 0.f : 1.f, m1 = 1.f - m0;
        a0 += m0 * v1; a1 += m0 * v1 * v1; a2 += m1 * v1; a3 += m1 * v1 * v1;
        b0 += m0 * v2; b1 += m0 * v2 * v2; b2 += m1 * v2; b3 += m1 * v2 * v2;
    }
    __shared__ float red[4][8][64];
    red[grp][0][ch] = a0; red[grp][1][ch] = a1; red[grp][2][ch] = a2; red[grp][3][ch] = a3;
    red[grp][4][ch] = b0; red[grp][5][ch] = b1; red[grp][6][ch] = b2; red[grp][7][ch] = b3;
    __syncthreads();
    for (int tt = t; tt < 512; tt += 256) {
        int j = tt >> 6, c = tt & 63;
        float s = red[0][j][c] + red[1][j][c] + red[2][j][c] + red[3][j][c];
        atomicAdd(&segsum[j * 64 + c], s);
    }
}

// ------- kernel 3: stats + segment-norm + midmini + concat + final + BN-sums --
__global__ __launch_bounds__(256) void k_tail(
    const float* __restrict__ y1, const float* __restrict__ y2,
    const float* __restrict__ segsum, const int* __restrict__ stacklen,
    const float* __restrict__ w_midmini, const float* __restrict__ w_final,
    float* __restrict__ outpre, float* __restrict__ bnsum, float* __restrict__ bnsq)
{
    __shared__ __align__(16) float sstat[4][2][64];   // [combo][mean|rstd][ch]
    __shared__ __align__(16) float sbuf[8][64];
    __shared__ __align__(16) float xc[8][128];
    __shared__ float lsum[2][128], lsq[2][128];
    const int n0 = blockIdx.x * 8;
    const int t = threadIdx.x;
    const int len0 = stacklen[0];

    {   // inline segfin: 256 threads = 4 combos x 64 ch
        int combo = t >> 6, ch = t & 63;
        float cnt = (float)max((combo & 1) ? (NQ - len0) : len0, 1);
        float S = segsum[(combo * 2 + 0) * 64 + ch];
        float Q = segsum[(combo * 2 + 1) * 64 + ch];
        float mean = S / cnt;
        float var = Q / cnt - mean * mean;
        sstat[combo][0][ch] = mean;
        sstat[combo][1][ch] = rsqrtf(fmaxf(var, 0.f) + EPSN);
    }
    __syncthreads();

    for (int tt = t; tt < 8 * 64; tt += 256) {
        int r = tt >> 6, d = tt & 63;
        int n = n0 + r;
        int s = (n >= len0) ? 1 : 0;
        float x1n = (y1[(size_t)n * DH + d] - sstat[s][0][d]) * sstat[s][1][d];
        float x2n = (y2[(size_t)n * DH + d] - sstat[2 + s][0][d]) * sstat[2 + s][1][d];
        xc[r][d] = x1n;
        sbuf[r][d] = x1n + x2n;
    }
    __syncthreads();

    for (int tt = t; tt < 8 * 64; tt += 256) {
        int r = tt >> 6, d = tt & 63;
        float a = 0.f;
        const float4* wmr = (const float4*)&w_midmini[(size_t)d * 64];
        const float4* sv = (const float4*)&sbuf[r][0];
        #pragma unroll
        for (int e4 = 0; e4 < 16; ++e4) {
            float4 w4 = wmr[e4], s4 = sv[e4];
            a += w4.x * s4.x + w4.y * s4.y + w4.z * s4.z + w4.w * s4.w;
        }
        xc[r][64 + d] = a;
    }
    __syncthreads();

    {
        const int j = t & 127;
        const int g = t >> 7;
        float o0 = 0.f, o1 = 0.f, o2 = 0.f, o3 = 0.f;
        const float4* wfr = (const float4*)&w_final[(size_t)j * 128];
        #pragma unroll 8
        for (int i4 = 0; i4 < 32; ++i4) {
            float4 wf = wfr[i4];
            float4 a0 = *(const float4*)&xc[g + 0][i4 * 4];
            float4 a1 = *(const float4*)&xc[g + 2][i4 * 4];
            float4 a2 = *(const float4*)&xc[g + 4][i4 * 4];
            float4 a3 = *(const float4*)&xc[g + 6][i4 * 4];
            o0 += wf.x * a0.x + wf.y * a0.y + wf.z * a0.z + wf.w * a0.w;
            o1 += wf.x * a1.x + wf.y * a1.y + wf.z * a1.z + wf.w * a1.w;
            o2 += wf.x * a2.x + wf.y * a2.y + wf.z * a2.z + wf.w * a2.w;
            o3 += wf.x * a3.x + wf.y * a3.y + wf.z * a3.z + wf.w * a3.w;
        }
        outpre[(size_t)(n0 + g + 0) * CH + j] = o0;
        outpre[(size_t)(n0 + g + 2) * CH + j] = o1;
        outpre[(size_t)(n0 + g + 4) * CH + j] = o2;
        outpre[(size_t)(n0 + g + 6) * CH + j] = o3;
        // fused BN partial sums
        lsum[g][j] = o0 + o1 + o2 + o3;
        lsq[g][j]  = o0 * o0 + o1 * o1 + o2 * o2 + o3 * o3;
        __syncthreads();
        if (g == 0) {
            atomicAdd(&bnsum[j], lsum[0][j] + lsum[1][j]);
            atomicAdd(&bnsq[j],  lsq[0][j] + lsq[1][j]);
        }
    }
}

// ---------------- kernel 5: BN apply + relu ----------------------------------
__global__ __launch_bounds__(256) void k_bnapply(const float* __restrict__ outpre,
    const float* __restrict__ bnsum, const float* __restrict__ bnsq,
    const float* __restrict__ gamma, const float* __restrict__ beta,
    float* __restrict__ out)
{
    int e4 = blockIdx.x * 256 + threadIdx.x;
    if (e4 >= NQ * CH / 4) return;
    int j0 = (e4 * 4) & 127;
    float4 v = ((const float4*)outpre)[e4];
    float vv[4] = {v.x, v.y, v.z, v.w};
    float res[4];
    #pragma unroll
    for (int i = 0; i < 4; ++i) {
        int j = j0 + i;
        float mean = bnsum[j] * (1.0f / NQ);
        float var = bnsq[j] * (1.0f / NQ) - mean * mean;
        float rstd = rsqrtf(fmaxf(var, 0.f) + EPSN);
        float r = (vv[i] - mean) * rstd * gamma[j] + beta[j];
        res[i] = fmaxf(r, 0.f);
    }
    ((float4*)out)[e4] = make_float4(res[0], res[1], res[2], res[3]);
}

extern "C" void kernel_launch(void* const* d_in, const int* in_sizes, int n_in,
                              void* d_out, int out_size, void* d_ws, size_t ws_size,
                              hipStream_t stream) {
    const float* q_pts     = (const float*)d_in[0];
    const float* s_pts     = (const float*)d_in[1];
    const int*   inds      = (const int*)d_in[2];
    const float* x         = (const float*)d_in[3];
    const int*   stacklen  = (const int*)d_in[4];
    const float* kp_mini   = (const float*)d_in[5];
    const float* w_mini    = (const float*)d_in[6];
    const float* kp_mid    = (const float*)d_in[7];
    const float* w_mid     = (const float*)d_in[8];
    const float* w_midmini = (const float*)d_in[9];
    const float* w_final   = (const float*)d_in[10];
    const float* gamma     = (const float*)d_in[11];
    const float* beta      = (const float*)d_in[12];

    float* ws      = (float*)d_ws;
    float* rowsum  = ws + OFF_ROWSUM;
    float* y1      = ws + OFF_Y1;
    float* y2      = ws + OFF_Y2;
    float* segsum  = ws + OFF_SEGSUM;
    float* bnsum   = ws + OFF_BNSUM;
    float* bnsq    = ws + OFF_BNSQ;
    float* outpre  = ws + OFF_OUTPRE;
    unsigned short* wswz = (unsigned short*)(ws + OFF_WSWZ);
    unsigned short* P    = (unsigned short*)(ws + OFF_P);

    // zero segsum(512) + bnsum(128) + bnsq(128)
    hipMemsetAsync(segsum, 0, 768 * sizeof(float), stream);

    if (ws_size >= (size_t)TOT_FLOATS * sizeof(float)) {
        k_prep<<<5000 + 1280, 256, 0, stream>>>(x, rowsum, w_mini, w_mid, wswz);
        k_gather<<<NQ / 8, 256, 0, stream>>>(q_pts, s_pts, inds, x, kp_mini, kp_mid,
                                             rowsum, P);
        dim3 mg((NMT + 7) / 8, 2);
        k_mfma<<<mg, 256, 0, stream>>>(P, wswz, stacklen, y1, y2, segsum);
    } else {
        k_prep<<<5000, 256, 0, stream>>>(x, rowsum, w_mini, w_mid, wswz);
        k_kpconv<<<NQ / 4, 256, 0, stream>>>(q_pts, s_pts, inds, x, kp_mini, kp_mid,
                                             w_mini, w_mid, rowsum, y1, y2);
        k_segpart<<<256, 256, 0, stream>>>(y1, y2, stacklen, segsum);
    }

    k_tail<<<NQ / 8, 256, 0, stream>>>(y1, y2, segsum, stacklen, w_midmini, w_final,
                                       outpre, bnsum, bnsq);
    k_bnapply<<<(NQ * CH / 4 + 255) / 256, 256, 0, stream>>>(outpre, bnsum, bnsq,
                                                             gamma, beta, (float*)d_out);
}

// Round 6
// 263.043 us; speedup vs baseline: 4.3977x; 1.1249x over previous
//
#include <hip/hip_runtime.h>
#include <math.h>

#define NQ 20000
#define MS 20000
#define HN 32
#define CH 128
#define DH 64
#define KTOT 20
#define KMINI 7
#define EPSN 1e-5f
#define KDIM 2560            // KTOT*CH
#define NKT 80               // KDIM/32
#define NMT 1250             // NQ/16
#define KT_Y1 28             // kt < 28 -> y1 (k<7), else y2

// workspace layout (in float units)
#define OFF_ROWSUM 0
#define OFF_Y1     20480
#define OFF_Y2     (OFF_Y1 + NQ*DH)
#define OFF_SEG    (OFF_Y2 + NQ*DH)           // 512 (unused, kept for layout)
#define OFF_SEGSUM (OFF_SEG + 512)            // 512, zeroed
#define OFF_BNSUM  (OFF_SEGSUM + 512)         // 128, zeroed
#define OFF_BNSQ   (OFF_BNSUM + 128)          // 128, zeroed
#define OFF_OUTPRE (OFF_BNSQ + 128)           // NQ*CH
#define OFF_WSWZ   (OFF_OUTPRE + NQ*CH)       // 327680 ushort = 163840 floats
#define OFF_P      (OFF_WSWZ + 163840)        // NQ*KDIM ushort (frag-ordered)
#define OFF_CFRAG  (OFF_P + NQ*KDIM/2)        // 16384 ushort = 8192 floats
#define TOT_FLOATS (OFF_CFRAG + 8192)

typedef __attribute__((ext_vector_type(8))) short bf16x8;
typedef __attribute__((ext_vector_type(4))) float f32x4;
typedef __attribute__((ext_vector_type(4))) unsigned short us4;

static __device__ inline unsigned short f2bf(float f) {
    unsigned int u = __float_as_uint(f);
    unsigned int r = (u + 0x7fffu + ((u >> 16) & 1u)) >> 16;
    return (unsigned short)r;
}

// --- kernel P: rowsum (<5000) + weight swizzle (<6280) + fused-C frags (rest) -
__global__ __launch_bounds__(256) void k_prep(
    const float* __restrict__ x, float* __restrict__ rowsum,
    const float* __restrict__ w_mini, const float* __restrict__ w_mid,
    const float* __restrict__ w_midmini, const float* __restrict__ w_final,
    unsigned short* __restrict__ wswz, unsigned short* __restrict__ cfrag)
{
    if (blockIdx.x < 5000) {
        int row = blockIdx.x * 4 + (threadIdx.x >> 6);
        int lane = threadIdx.x & 63;
        if (row >= MS) return;
        double s = (double)x[row * CH + lane] + (double)x[row * CH + 64 + lane];
        #pragma unroll
        for (int off = 32; off > 0; off >>= 1) s += __shfl_down(s, off, 64);
        if (lane == 0) rowsum[row] = (float)s;
    } else if (blockIdx.x < 6280) {
        int gid = (blockIdx.x - 5000) * 256 + threadIdx.x;
        if (gid >= NKT * 8 * 512) return;
        int j = gid & 7;
        int l = (gid >> 3) & 63;
        int ntkt = gid >> 9;
        int nt = ntkt & 7;
        int kt = ntkt >> 3;
        int kg = kt * 32 + ((l >> 4) << 3) + j;
        int d  = nt * 16 + (l & 15);
        int k = kg >> 7, c = kg & 127;
        float v = 0.0f;
        if (k < KMINI && d < DH)        v = w_mini[((size_t)k * CH + c) * DH + d];
        else if (k >= KMINI && d >= DH) v = w_mid[((size_t)(k - KMINI) * CH + c) * DH + (d - DH)];
        wswz[gid] = f2bf(v);
    } else {
        // fused tail matrix C[i][j] = (i<64 ? w_final[j][i] : 0) + D[i&63][j],
        // D[e][j] = sum_d w_midmini[d][e] * w_final[j][64+d]; store B-frag order.
        int b2 = blockIdx.x - 6280;            // 0..31 -> (kt, nt)
        int kt = b2 >> 3, nt = b2 & 7;
        for (int e = threadIdx.x; e < 512; e += 256) {
            int l = e >> 3, j = e & 7;
            int i = kt * 32 + ((l >> 4) << 3) + j;     // 0..127
            int jcol = nt * 16 + (l & 15);             // 0..127
            const float* wfr = &w_final[(size_t)jcol * 128 + 64];
            int ec = i & 63;
            float dsum = 0.f;
            #pragma unroll 8
            for (int dd = 0; dd < 64; ++dd)
                dsum += w_midmini[dd * 64 + ec] * wfr[dd];
            float cv = dsum + ((i < 64) ? w_final[(size_t)jcol * 128 + i] : 0.f);
            cfrag[(size_t)(kt * 8 + nt) * 512 + e] = f2bf(cv);
        }
    }
}

// ---------------- kernel G: gather + influence -> Pfrag (MFMA A-frag order) ---
__global__ __launch_bounds__(256) void k_gather(
    const float* __restrict__ q_pts, const float* __restrict__ s_pts,
    const int* __restrict__ inds, const float* __restrict__ x,
    const float* __restrict__ kp_mini, const float* __restrict__ kp_mid,
    const float* __restrict__ rowsum,
    unsigned short* __restrict__ P)
{
    __shared__ __align__(16) float kpts[KTOT][3];
    __shared__ __align__(16) float nb[256][3];
    __shared__ int   nidx[256];
    __shared__ int   vcnt[8];
    __shared__ float winv[8];
    __shared__ __align__(16) float wts[8][HN][KTOT];

    const int t = threadIdx.x;
    const int n0 = blockIdx.x * 8;

    if (t < KTOT * 3) {
        int k = t / 3, j = t % 3;
        kpts[k][j] = (k < KMINI) ? kp_mini[k * 3 + j] : kp_mid[(k - KMINI) * 3 + j];
    }
    if (t < 8) vcnt[t] = 0;
    __syncthreads();

    {   // 256 threads = 8 rows x 32 neighbors
        int r = t >> 5, h = t & 31;
        int n = n0 + r;
        int idx = inds[n * HN + h];
        nidx[t] = idx;
        float qx = q_pts[n * 3 + 0], qy = q_pts[n * 3 + 1], qz = q_pts[n * 3 + 2];
        nb[t][0] = s_pts[idx * 3 + 0] - qx;
        nb[t][1] = s_pts[idx * 3 + 1] - qy;
        nb[t][2] = s_pts[idx * 3 + 2] - qz;
        if (rowsum[idx] > 0.0f) atomicAdd(&vcnt[r], 1);
    }
    __syncthreads();
    if (t < 8) winv[t] = 1.0f / (float)max(vcnt[t], 1);
    __syncthreads();

    for (int tt = t; tt < 8 * HN * KTOT; tt += 256) {
        int r = tt / (HN * KTOT);
        int rem = tt % (HN * KTOT);
        int h = rem / KTOT, k = rem % KTOT;
        float dx = nb[r * HN + h][0] - kpts[k][0];
        float dy = nb[r * HN + h][1] - kpts[k][1];
        float dz = nb[r * HN + h][2] - kpts[k][2];
        float sq = dx * dx + dy * dy + dz * dz;
        float dist = sqrtf(fmaxf(sq, 1e-12f));
        float w = fmaxf(1.0f - dist * (1.0f / 0.6f), 0.0f);
        wts[r][h][k] = w * winv[r];
    }
    __syncthreads();

    const int r = t >> 5;
    const int c4 = t & 31;
    float acc[KTOT][4];
    #pragma unroll
    for (int k = 0; k < KTOT; ++k) {
        acc[k][0] = 0.f; acc[k][1] = 0.f; acc[k][2] = 0.f; acc[k][3] = 0.f;
    }
    const float* wbase = &wts[r][0][0];
    const int* nid = &nidx[r * HN];
    #pragma unroll 2
    for (int h = 0; h < HN; ++h) {
        int idx = nid[h];
        float4 xv = *(const float4*)&x[(size_t)idx * CH + c4 * 4];
        const float4* wp = (const float4*)(wbase + h * KTOT);
        float warr[20];
        *(float4*)&warr[0]  = wp[0];
        *(float4*)&warr[4]  = wp[1];
        *(float4*)&warr[8]  = wp[2];
        *(float4*)&warr[12] = wp[3];
        *(float4*)&warr[16] = wp[4];
        #pragma unroll
        for (int k = 0; k < KTOT; ++k) {
            float wv = warr[k];
            acc[k][0] += wv * xv.x; acc[k][1] += wv * xv.y;
            acc[k][2] += wv * xv.z; acc[k][3] += wv * xv.w;
        }
    }
    const int n = n0 + r;
    const int mt = n >> 4, m15 = n & 15;
    const int lq = (c4 & 7) >> 1;
    const int l = lq * 16 + m15;
    const int j = (c4 & 1) * 4;
    #pragma unroll
    for (int k = 0; k < KTOT; ++k) {
        int kt = k * 4 + (c4 >> 3);
        us4 v;
        v[0] = f2bf(acc[k][0]); v[1] = f2bf(acc[k][1]);
        v[2] = f2bf(acc[k][2]); v[3] = f2bf(acc[k][3]);
        *(us4*)(P + ((size_t)mt * NKT + kt) * 512 + l * 8 + j) = v;
    }
}

// ---------------- kernel M: frag-direct MFMA GEMM + fused segment stats -------
__global__ __launch_bounds__(256) void k_mfma(
    const unsigned short* __restrict__ P, const unsigned short* __restrict__ wswz,
    const int* __restrict__ stacklen,
    float* __restrict__ y1, float* __restrict__ y2, float* __restrict__ segsum)
{
    const int t = threadIdx.x;
    const int l = t & 63;
    const int w = t >> 6;
    const int chunk = blockIdx.y;
    const int mtb = blockIdx.x * 8 + w * 2;
    if (mtb >= NMT) return;
    const int kb = chunk ? KT_Y1 : 0;
    const int ke = chunk ? NKT : KT_Y1;
    const int ntb = chunk ? 4 : 0;

    f32x4 acc[2][4];
    #pragma unroll
    for (int i = 0; i < 2; ++i)
        #pragma unroll
        for (int q = 0; q < 4; ++q) acc[i][q] = (f32x4){0.f, 0.f, 0.f, 0.f};

    const size_t astride = (size_t)NKT * 512;
    const unsigned short* a0p = P + (size_t)mtb * astride + l * 8;
    const unsigned short* a1p = (mtb + 1 < NMT) ? a0p + astride : a0p;
    const unsigned short* bp = wswz + l * 8;

    #pragma unroll 2
    for (int kt = kb; kt < ke; ++kt) {
        bf16x8 a0 = *(const bf16x8*)(a0p + (size_t)kt * 512);
        bf16x8 a1 = *(const bf16x8*)(a1p + (size_t)kt * 512);
        #pragma unroll
        for (int q = 0; q < 4; ++q) {
            bf16x8 b = *(const bf16x8*)(bp + (size_t)((kt * 8) + ntb + q) * 512);
            acc[0][q] = __builtin_amdgcn_mfma_f32_16x16x32_bf16(a0, b, acc[0][q], 0, 0, 0);
            acc[1][q] = __builtin_amdgcn_mfma_f32_16x16x32_bf16(a1, b, acc[1][q], 0, 0, 0);
        }
    }

    const int len0 = stacklen[0];
    float* yb = chunk ? y2 : y1;
    const int quad = l >> 4, c16 = l & 15;
    const int base_sum = (chunk * 2) * 2 * 64;

    #pragma unroll
    for (int i = 0; i < 2; ++i) {
        int mt = mtb + i;
        if (mt >= NMT) break;
        bool all0 = (mt * 16 + 15 < len0);
        bool all1 = (mt * 16 >= len0);
        #pragma unroll
        for (int q = 0; q < 4; ++q) {
            float s0 = 0.f, q0 = 0.f, s1 = 0.f, q1 = 0.f;
            #pragma unroll
            for (int reg = 0; reg < 4; ++reg) {
                int row = mt * 16 + quad * 4 + reg;
                float v = acc[i][q][reg];
                yb[(size_t)row * DH + q * 16 + c16] = v;
                if (row < len0) { s0 += v; q0 += v * v; }
                else            { s1 += v; q1 += v * v; }
            }
            s0 += __shfl_xor(s0, 16); s0 += __shfl_xor(s0, 32);
            q0 += __shfl_xor(q0, 16); q0 += __shfl_xor(q0, 32);
            s1 += __shfl_xor(s1, 16); s1 += __shfl_xor(s1, 32);
            q1 += __shfl_xor(q1, 16); q1 += __shfl_xor(q1, 32);
            if (quad == 0) {
                int ch = q * 16 + c16;
                if (!all1) {
                    atomicAdd(&segsum[base_sum + 0 * 64 + ch], s0);
                    atomicAdd(&segsum[base_sum + 1 * 64 + ch], q0);
                }
                if (!all0) {
                    atomicAdd(&segsum[base_sum + 2 * 64 + ch], s1);
                    atomicAdd(&segsum[base_sum + 3 * 64 + ch], q1);
                }
            }
        }
    }
}

// -------- kernel T: fused tail GEMM (norm folded into A) + BN partials --------
// out[n][j] = sum_i ((ycat[n][i]-mean)*rstd) * C[i][j];  313 blocks x 64 rows.
__global__ __launch_bounds__(256) void k_tailmm(
    const float* __restrict__ y1, const float* __restrict__ y2,
    const float* __restrict__ segsum, const int* __restrict__ stacklen,
    const unsigned short* __restrict__ cfrag,
    float* __restrict__ outpre, float* __restrict__ bnsum, float* __restrict__ bnsq)
{
    __shared__ __align__(16) unsigned short alds[64 * 136];   // pitch 136 (2-way alias)
    __shared__ float sstat[4][2][64];
    const int t = threadIdx.x;
    const int mb = blockIdx.x * 64;
    const int len0 = stacklen[0];

    {   // inline stats: 4 combos x 64 ch
        int combo = t >> 6, ch = t & 63;
        float cnt = (float)max((combo & 1) ? (NQ - len0) : len0, 1);
        float S = segsum[(combo * 2 + 0) * 64 + ch];
        float Q = segsum[(combo * 2 + 1) * 64 + ch];
        float mean = S / cnt;
        float var = Q / cnt - mean * mean;
        sstat[combo][0][ch] = mean;
        sstat[combo][1][ch] = rsqrtf(fmaxf(var, 0.f) + EPSN);
    }
    __syncthreads();

    // stage normalized A (bf16): 64 rows x 128 ch, 4 ch per unit
    for (int tt = t; tt < 64 * 32; tt += 256) {
        int r = tt >> 5, c4 = tt & 31;
        int n = mb + r;
        us4 v4 = (us4){0, 0, 0, 0};
        if (n < NQ) {
            int s = (n >= len0) ? 1 : 0;
            int c = c4 * 4;
            if (c < 64) {
                float4 yv = *(const float4*)&y1[(size_t)n * DH + c];
                v4[0] = f2bf((yv.x - sstat[s][0][c + 0]) * sstat[s][1][c + 0]);
                v4[1] = f2bf((yv.y - sstat[s][0][c + 1]) * sstat[s][1][c + 1]);
                v4[2] = f2bf((yv.z - sstat[s][0][c + 2]) * sstat[s][1][c + 2]);
                v4[3] = f2bf((yv.w - sstat[s][0][c + 3]) * sstat[s][1][c + 3]);
            } else {
                int c2 = c - 64;
                float4 yv = *(const float4*)&y2[(size_t)n * DH + c2];
                v4[0] = f2bf((yv.x - sstat[2 + s][0][c2 + 0]) * sstat[2 + s][1][c2 + 0]);
                v4[1] = f2bf((yv.y - sstat[2 + s][0][c2 + 1]) * sstat[2 + s][1][c2 + 1]);
                v4[2] = f2bf((yv.z - sstat[2 + s][0][c2 + 2]) * sstat[2 + s][1][c2 + 2]);
                v4[3] = f2bf((yv.w - sstat[2 + s][0][c2 + 3]) * sstat[2 + s][1][c2 + 3]);
            }
        }
        *(us4*)(alds + r * 136 + c4 * 4) = v4;
    }
    __syncthreads();

    const int l = t & 63, w = t >> 6;
    f32x4 acc[8];
    #pragma unroll
    for (int q = 0; q < 8; ++q) acc[q] = (f32x4){0.f, 0.f, 0.f, 0.f};

    const unsigned short* ap = alds + (w * 16 + (l & 15)) * 136 + ((l >> 4) << 3);
    const unsigned short* bp = cfrag + l * 8;
    #pragma unroll
    for (int kt = 0; kt < 4; ++kt) {
        bf16x8 a = *(const bf16x8*)(ap + kt * 32);
        #pragma unroll
        for (int nt = 0; nt < 8; ++nt) {
            bf16x8 b = *(const bf16x8*)(bp + (size_t)((kt * 8 + nt) << 9));
            acc[nt] = __builtin_amdgcn_mfma_f32_16x16x32_bf16(a, b, acc[nt], 0, 0, 0);
        }
    }

    const int quad = l >> 4, c16 = l & 15;
    #pragma unroll
    for (int nt = 0; nt < 8; ++nt) {
        float s = 0.f, q = 0.f;
        #pragma unroll
        for (int reg = 0; reg < 4; ++reg) {
            int row = mb + w * 16 + quad * 4 + reg;
            float v = acc[nt][reg];
            if (row < NQ) outpre[(size_t)row * CH + nt * 16 + c16] = v;
            else v = 0.f;
            s += v; q += v * v;
        }
        s += __shfl_xor(s, 16); s += __shfl_xor(s, 32);
        q += __shfl_xor(q, 16); q += __shfl_xor(q, 32);
        if (quad == 0) {
            atomicAdd(&bnsum[nt * 16 + c16], s);
            atomicAdd(&bnsq[nt * 16 + c16], q);
        }
    }
}

// ---------------- FALLBACK: R1 fused kpconv (if ws too small) -----------------
__global__ __launch_bounds__(256) void k_kpconv(
    const float* __restrict__ q_pts, const float* __restrict__ s_pts,
    const int* __restrict__ inds, const float* __restrict__ x,
    const float* __restrict__ kp_mini, const float* __restrict__ kp_mid,
    const float* __restrict__ w_mini, const float* __restrict__ w_mid,
    const float* __restrict__ rowsum,
    float* __restrict__ y1, float* __restrict__ y2)
{
    __shared__ __align__(16) float kpts[KTOT][3];
    __shared__ __align__(16) float nb[128][3];
    __shared__ int   nidx[128];
    __shared__ int   vcnt[4];
    __shared__ float winv[4];
    __shared__ __align__(16) float wts[4][HN][KTOT];
    __shared__ __align__(16) float wt[KTOT][CH][4];
    __shared__ __align__(16) float part[128][4];

    const int t = threadIdx.x;
    const int n0 = blockIdx.x * 4;

    if (t < KTOT * 3) {
        int k = t / 3, j = t % 3;
        kpts[k][j] = (k < KMINI) ? kp_mini[k * 3 + j] : kp_mid[(k - KMINI) * 3 + j];
    }
    if (t < 4) vcnt[t] = 0;
    __syncthreads();

    if (t < 128) {
        int r = t >> 5, h = t & 31;
        int n = n0 + r;
        int idx = inds[n * HN + h];
        nidx[t] = idx;
        float qx = q_pts[n * 3 + 0], qy = q_pts[n * 3 + 1], qz = q_pts[n * 3 + 2];
        nb[t][0] = s_pts[idx * 3 + 0] - qx;
        nb[t][1] = s_pts[idx * 3 + 1] - qy;
        nb[t][2] = s_pts[idx * 3 + 2] - qz;
        if (rowsum[idx] > 0.0f) atomicAdd(&vcnt[r], 1);
    }
    __syncthreads();
    if (t < 4) winv[t] = 1.0f / (float)max(vcnt[t], 1);
    __syncthreads();

    for (int tt = t; tt < 4 * HN * KTOT; tt += 256) {
        int r = tt / (HN * KTOT);
        int rem = tt % (HN * KTOT);
        int h = rem / KTOT, k = rem % KTOT;
        float dx = nb[r * HN + h][0] - kpts[k][0];
        float dy = nb[r * HN + h][1] - kpts[k][1];
        float dz = nb[r * HN + h][2] - kpts[k][2];
        float sq = dx * dx + dy * dy + dz * dz;
        float dist = sqrtf(fmaxf(sq, 1e-12f));
        float w = fmaxf(1.0f - dist * (1.0f / 0.6f), 0.0f);
        wts[r][h][k] = w * winv[r];
    }
    __syncthreads();

    {
        const int g = t >> 7;
        const int c = t & 127;
        for (int rr = 0; rr < 2; ++rr) {
            const int r = g + rr * 2;
            float acc[KTOT];
            #pragma unroll
            for (int k = 0; k < KTOT; ++k) acc[k] = 0.0f;
            for (int h = 0; h < HN; ++h) {
                int idx = nidx[r * HN + h];
                float xv = x[(size_t)idx * CH + c];
                const float4* wp = (const float4*)&wts[r][h][0];
                float4 wa = wp[0], wb = wp[1], wc = wp[2], wd = wp[3], we = wp[4];
                acc[0]  += wa.x * xv; acc[1]  += wa.y * xv; acc[2]  += wa.z * xv; acc[3]  += wa.w * xv;
                acc[4]  += wb.x * xv; acc[5]  += wb.y * xv; acc[6]  += wb.z * xv; acc[7]  += wb.w * xv;
                acc[8]  += wc.x * xv; acc[9]  += wc.y * xv; acc[10] += wc.z * xv; acc[11] += wc.w * xv;
                acc[12] += wd.x * xv; acc[13] += wd.y * xv; acc[14] += wd.z * xv; acc[15] += wd.w * xv;
                acc[16] += we.x * xv; acc[17] += we.y * xv; acc[18] += we.z * xv; acc[19] += we.w * xv;
            }
            #pragma unroll
            for (int k = 0; k < KTOT; ++k) wt[k][c][r] = acc[k];
        }
    }
    __syncthreads();

    {
        const int d = t & 127;
        const int half = t >> 7;
        const int c0 = half * 64;
        float o0 = 0.f, o1 = 0.f, o2 = 0.f, o3 = 0.f;
        if (d < DH) {
            for (int k = 0; k < KMINI; ++k) {
                const float* wp = &w_mini[((size_t)k * CH + c0) * DH + d];
                for (int c = c0; c < c0 + 64; ++c) {
                    float wv = *wp; wp += DH;
                    const float4 wtv = *(const float4*)&wt[k][c][0];
                    o0 += wv * wtv.x; o1 += wv * wtv.y; o2 += wv * wtv.z; o3 += wv * wtv.w;
                }
            }
        } else {
            const int dd = d - DH;
            for (int k = KMINI; k < KTOT; ++k) {
                const float* wp = &w_mid[((size_t)(k - KMINI) * CH + c0) * DH + dd];
                for (int c = c0; c < c0 + 64; ++c) {
                    float wv = *wp; wp += DH;
                    const float4 wtv = *(const float4*)&wt[k][c][0];
                    o0 += wv * wtv.x; o1 += wv * wtv.y; o2 += wv * wtv.z; o3 += wv * wtv.w;
                }
            }
        }
        if (half == 1) { part[d][0] = o0; part[d][1] = o1; part[d][2] = o2; part[d][3] = o3; }
        __syncthreads();
        if (half == 0) {
            o0 += part[d][0]; o1 += part[d][1]; o2 += part[d][2]; o3 += part[d][3];
            if (d < DH) {
                y1[(size_t)(n0 + 0) * DH + d] = o0;
                y1[(size_t)(n0 + 1) * DH + d] = o1;
                y1[(size_t)(n0 + 2) * DH + d] = o2;
                y1[(size_t)(n0 + 3) * DH + d] = o3;
            } else {
                const int dd = d - DH;
                y2[(size_t)(n0 + 0) * DH + dd] = o0;
                y2[(size_t)(n0 + 1) * DH + dd] = o1;
                y2[(size_t)(n0 + 2) * DH + dd] = o2;
                y2[(size_t)(n0 + 3) * DH + dd] = o3;
            }
        }
    }
}

// -------- fallback-only: parallel per-segment partial sums --------------------
__global__ __launch_bounds__(256) void k_segpart(
    const float* __restrict__ y1, const float* __restrict__ y2,
    const int* __restrict__ stacklen, float* __restrict__ segsum)
{
    const int t = threadIdx.x;
    const int ch = t & 63, grp = t >> 6;
    const int len0 = stacklen[0];
    float a0 = 0.f, a1 = 0.f, a2 = 0.f, a3 = 0.f;
    float b0 = 0.f, b1 = 0.f, b2 = 0.f, b3 = 0.f;
    for (int r = blockIdx.x * 4 + grp; r < NQ; r += 256 * 4) {
        float v1 = y1[(size_t)r * DH + ch];
        float v2 = y2[(size_t)r * DH + ch];
        bool in1 = (r >= len0);
        float m0 = in1 ? 0.f : 1.f, m1 = 1.f - m0;
        a0 += m0 * v1; a1 += m0 * v1 * v1; a2 += m1 * v1; a3 += m1 * v1 * v1;
        b0 += m0 * v2; b1 += m0 * v2 * v2; b2 += m1 * v2; b3 += m1 * v2 * v2;
    }
    __shared__ float red[4][8][64];
    red[grp][0][ch] = a0; red[grp][1][ch] = a1; red[grp][2][ch] = a2; red[grp][3][ch] = a3;
    red[grp][4][ch] = b0; red[grp][5][ch] = b1; red[grp][6][ch] = b2; red[grp][7][ch] = b3;
    __syncthreads();
    for (int tt = t; tt < 512; tt += 256) {
        int j = tt >> 6, c = tt & 63;
        float s = red[0][j][c] + red[1][j][c] + red[2][j][c] + red[3][j][c];
        atomicAdd(&segsum[j * 64 + c], s);
    }
}

// ------- fallback-only: old tail --------------------------------------------
__global__ __launch_bounds__(256) void k_tail(
    const float* __restrict__ y1, const float* __restrict__ y2,
    const float* __restrict__ segsum, const int* __restrict__ stacklen,
    const float* __restrict__ w_midmini, const float* __restrict__ w_final,
    float* __restrict__ outpre, float* __restrict__ bnsum, float* __restrict__ bnsq)
{
    __shared__ __align__(16) float sstat[4][2][64];
    __shared__ __align__(16) float sbuf[8][64];
    __shared__ __align__(16) float xc[8][128];
    __shared__ float lsum[2][128], lsq[2][128];
    const int n0 = blockIdx.x * 8;
    const int t = threadIdx.x;
    const int len0 = stacklen[0];

    {
        int combo = t >> 6, ch = t & 63;
        float cnt = (float)max((combo & 1) ? (NQ - len0) : len0, 1);
        float S = segsum[(combo * 2 + 0) * 64 + ch];
        float Q = segsum[(combo * 2 + 1) * 64 + ch];
        float mean = S / cnt;
        float var = Q / cnt - mean * mean;
        sstat[combo][0][ch] = mean;
        sstat[combo][1][ch] = rsqrtf(fmaxf(var, 0.f) + EPSN);
    }
    __syncthreads();

    for (int tt = t; tt < 8 * 64; tt += 256) {
        int r = tt >> 6, d = tt & 63;
        int n = n0 + r;
        int s = (n >= len0) ? 1 : 0;
        float x1n = (y1[(size_t)n * DH + d] - sstat[s][0][d]) * sstat[s][1][d];
        float x2n = (y2[(size_t)n * DH + d] - sstat[2 + s][0][d]) * sstat[2 + s][1][d];
        xc[r][d] = x1n;
        sbuf[r][d] = x1n + x2n;
    }
    __syncthreads();

    for (int tt = t; tt < 8 * 64; tt += 256) {
        int r = tt >> 6, d = tt & 63;
        float a = 0.f;
        const float4* wmr = (const float4*)&w_midmini[(size_t)d * 64];
        const float4* sv = (const float4*)&sbuf[r][0];
        #pragma unroll
        for (int e4 = 0; e4 < 16; ++e4) {
            float4 w4 = wmr[e4], s4 = sv[e4];
            a += w4.x * s4.x + w4.y * s4.y + w4.z * s4.z + w4.w * s4.w;
        }
        xc[r][64 + d] = a;
    }
    __syncthreads();

    {
        const int j = t & 127;
        const int g = t >> 7;
        float o0 = 0.f, o1 = 0.f, o2 = 0.f, o3 = 0.f;
        const float4* wfr = (const float4*)&w_final[(size_t)j * 128];
        #pragma unroll 8
        for (int i4 = 0; i4 < 32; ++i4) {
            float4 wf = wfr[i4];
            float4 a0 = *(const float4*)&xc[g + 0][i4 * 4];
            float4 a1 = *(const float4*)&xc[g + 2][i4 * 4];
            float4 a2 = *(const float4*)&xc[g + 4][i4 * 4];
            float4 a3 = *(const float4*)&xc[g + 6][i4 * 4];
            o0 += wf.x * a0.x + wf.y * a0.y + wf.z * a0.z + wf.w * a0.w;
            o1 += wf.x * a1.x + wf.y * a1.y + wf.z * a1.z + wf.w * a1.w;
            o2 += wf.x * a2.x + wf.y * a2.y + wf.z * a2.z + wf.w * a2.w;
            o3 += wf.x * a3.x + wf.y * a3.y + wf.z * a3.z + wf.w * a3.w;
        }
        outpre[(size_t)(n0 + g + 0) * CH + j] = o0;
        outpre[(size_t)(n0 + g + 2) * CH + j] = o1;
        outpre[(size_t)(n0 + g + 4) * CH + j] = o2;
        outpre[(size_t)(n0 + g + 6) * CH + j] = o3;
        lsum[g][j] = o0 + o1 + o2 + o3;
        lsq[g][j]  = o0 * o0 + o1 * o1 + o2 * o2 + o3 * o3;
        __syncthreads();
        if (g == 0) {
            atomicAdd(&bnsum[j], lsum[0][j] + lsum[1][j]);
            atomicAdd(&bnsq[j],  lsq[0][j] + lsq[1][j]);
        }
    }
}

// ---------------- kernel 5: BN apply + relu ----------------------------------
__global__ __launch_bounds__(256) void k_bnapply(const float* __restrict__ outpre,
    const float* __restrict__ bnsum, const float* __restrict__ bnsq,
    const float* __restrict__ gamma, const float* __restrict__ beta,
    float* __restrict__ out)
{
    int e4 = blockIdx.x * 256 + threadIdx.x;
    if (e4 >= NQ * CH / 4) return;
    int j0 = (e4 * 4) & 127;
    float4 v = ((const float4*)outpre)[e4];
    float vv[4] = {v.x, v.y, v.z, v.w};
    float res[4];
    #pragma unroll
    for (int i = 0; i < 4; ++i) {
        int j = j0 + i;
        float mean = bnsum[j] * (1.0f / NQ);
        float var = bnsq[j] * (1.0f / NQ) - mean * mean;
        float rstd = rsqrtf(fmaxf(var, 0.f) + EPSN);
        float r = (vv[i] - mean) * rstd * gamma[j] + beta[j];
        res[i] = fmaxf(r, 0.f);
    }
    ((float4*)out)[e4] = make_float4(res[0], res[1], res[2], res[3]);
}

extern "C" void kernel_launch(void* const* d_in, const int* in_sizes, int n_in,
                              void* d_out, int out_size, void* d_ws, size_t ws_size,
                              hipStream_t stream) {
    const float* q_pts     = (const float*)d_in[0];
    const float* s_pts     = (const float*)d_in[1];
    const int*   inds      = (const int*)d_in[2];
    const float* x         = (const float*)d_in[3];
    const int*   stacklen  = (const int*)d_in[4];
    const float* kp_mini   = (const float*)d_in[5];
    const float* w_mini    = (const float*)d_in[6];
    const float* kp_mid    = (const float*)d_in[7];
    const float* w_mid     = (const float*)d_in[8];
    const float* w_midmini = (const float*)d_in[9];
    const float* w_final   = (const float*)d_in[10];
    const float* gamma     = (const float*)d_in[11];
    const float* beta      = (const float*)d_in[12];

    float* ws      = (float*)d_ws;
    float* rowsum  = ws + OFF_ROWSUM;
    float* y1      = ws + OFF_Y1;
    float* y2      = ws + OFF_Y2;
    float* segsum  = ws + OFF_SEGSUM;
    float* bnsum   = ws + OFF_BNSUM;
    float* bnsq    = ws + OFF_BNSQ;
    float* outpre  = ws + OFF_OUTPRE;
    unsigned short* wswz  = (unsigned short*)(ws + OFF_WSWZ);
    unsigned short* P     = (unsigned short*)(ws + OFF_P);
    unsigned short* cfrag = (unsigned short*)(ws + OFF_CFRAG);

    // zero segsum(512) + bnsum(128) + bnsq(128)
    hipMemsetAsync(segsum, 0, 768 * sizeof(float), stream);

    if (ws_size >= (size_t)TOT_FLOATS * sizeof(float)) {
        k_prep<<<5000 + 1280 + 32, 256, 0, stream>>>(x, rowsum, w_mini, w_mid,
                                                     w_midmini, w_final, wswz, cfrag);
        k_gather<<<NQ / 8, 256, 0, stream>>>(q_pts, s_pts, inds, x, kp_mini, kp_mid,
                                             rowsum, P);
        dim3 mg((NMT + 7) / 8, 2);
        k_mfma<<<mg, 256, 0, stream>>>(P, wswz, stacklen, y1, y2, segsum);
        k_tailmm<<<(NQ + 63) / 64, 256, 0, stream>>>(y1, y2, segsum, stacklen, cfrag,
                                                     outpre, bnsum, bnsq);
    } else {
        k_prep<<<5000, 256, 0, stream>>>(x, rowsum, w_mini, w_mid,
                                         w_midmini, w_final, wswz, cfrag);
        k_kpconv<<<NQ / 4, 256, 0, stream>>>(q_pts, s_pts, inds, x, kp_mini, kp_mid,
                                             w_mini, w_mid, rowsum, y1, y2);
        k_segpart<<<256, 256, 0, stream>>>(y1, y2, stacklen, segsum);
        k_tail<<<NQ / 8, 256, 0, stream>>>(y1, y2, segsum, stacklen, w_midmini, w_final,
                                           outpre, bnsum, bnsq);
    }

    k_bnapply<<<(NQ * CH / 4 + 255) / 256, 256, 0, stream>>>(outpre, bnsum, bnsq,
                                                             gamma, beta, (float*)d_out);
}